// Round 1
// baseline (3632.583 us; speedup 1.0000x reference)
//
#include <hip/hip_runtime.h>
#include <math.h>

__device__ __forceinline__ float sigf(float v) { return 1.f / (1.f + __expf(-v)); }

// ---------------- GEMM: C[M,N] = A[M,K] @ W[K,N] (+bias) (+=C) ----------------
// 64x64 tile, BK=16, 256 threads, 4x4 per thread. M%64==0, K%16==0, N%4==0.
template<bool GATHER, bool BIAS, bool ACC>
__global__ __launch_bounds__(256) void gemm_kernel(
    const float* __restrict__ A, const float* __restrict__ W,
    const float* __restrict__ bias, float* __restrict__ C,
    int M, int N, int K)
{
  __shared__ float As[16][64];
  __shared__ float Bs[16][64];
  const int tid = threadIdx.x;
  const int m0 = blockIdx.x * 64;
  const int n0 = blockIdx.y * 64;
  const int tx = tid & 15;   // -> m
  const int ty = tid >> 4;   // -> n
  float acc[4][4];
#pragma unroll
  for (int i = 0; i < 4; i++)
#pragma unroll
    for (int j = 0; j < 4; j++) acc[i][j] = 0.f;

  const int ar  = tid >> 2;        // A row 0..63
  const int akc = (tid & 3) * 4;   // A k-col
  const int bkr = tid >> 4;        // B k-row 0..15
  const int bnc = (tid & 15) * 4;  // B n-col

  for (int k0 = 0; k0 < K; k0 += 16) {
    float4 av;
    if (GATHER) {
      // A(m,k) = x[b, s, t, d]: m=b*2048+t, k=s*256+d  (x is (4,3,2048,256))
      int m = m0 + ar; int bb = m >> 11; int t = m & 2047;
      int kk = k0 + akc; int s = kk >> 8; int d = kk & 255;
      av = *(const float4*)(A + ((size_t)((bb * 3 + s) * 2048 + t) << 8) + d);
    } else {
      av = *(const float4*)(A + (size_t)(m0 + ar) * K + (k0 + akc));
    }
    As[akc + 0][ar] = av.x;
    As[akc + 1][ar] = av.y;
    As[akc + 2][ar] = av.z;
    As[akc + 3][ar] = av.w;

    float4 bv = make_float4(0.f, 0.f, 0.f, 0.f);
    int nn = n0 + bnc;
    if (nn + 3 < N) bv = *(const float4*)(W + (size_t)(k0 + bkr) * N + nn);
    *(float4*)&Bs[bkr][bnc] = bv;
    __syncthreads();
#pragma unroll
    for (int k = 0; k < 16; k++) {
      float4 a4 = *(float4*)&As[k][tx * 4];
      float4 b4 = *(float4*)&Bs[k][ty * 4];
      float am[4] = {a4.x, a4.y, a4.z, a4.w};
      float bm[4] = {b4.x, b4.y, b4.z, b4.w};
#pragma unroll
      for (int i = 0; i < 4; i++)
#pragma unroll
        for (int j = 0; j < 4; j++) acc[i][j] += am[i] * bm[j];
    }
    __syncthreads();
  }
  const int nc = n0 + ty * 4;
  if (nc + 3 < N) {
    float4 b4 = make_float4(0.f, 0.f, 0.f, 0.f);
    if (BIAS) b4 = *(const float4*)(bias + nc);
#pragma unroll
    for (int i = 0; i < 4; i++) {
      int m = m0 + tx * 4 + i;
      float* cp = C + (size_t)m * N + nc;
      float4 o;
      o.x = acc[i][0] + b4.x;
      o.y = acc[i][1] + b4.y;
      o.z = acc[i][2] + b4.z;
      o.w = acc[i][3] + b4.w;
      if (ACC) {
        float4 p = *(float4*)cp;
        o.x += p.x; o.y += p.y; o.z += p.z; o.w += p.w;
      }
      *(float4*)cp = o;
    }
  }
}

// ---------------- LayerNorm over 512, in place. 1 wave per row ----------------
__global__ void ln512_kernel(float* __restrict__ xio, const float* __restrict__ g,
                             const float* __restrict__ b)
{
  const int row = blockIdx.x;
  const int lane = threadIdx.x;
  float* xr = xio + (size_t)row * 512;
  float4 v0 = *(float4*)(xr + lane * 4);
  float4 v1 = *(float4*)(xr + 256 + lane * 4);
  float sum = v0.x + v0.y + v0.z + v0.w + v1.x + v1.y + v1.z + v1.w;
#pragma unroll
  for (int o = 32; o >= 1; o >>= 1) sum += __shfl_xor(sum, o);
  const float mu = sum * (1.f / 512.f);
  float d[8] = {v0.x - mu, v0.y - mu, v0.z - mu, v0.w - mu,
                v1.x - mu, v1.y - mu, v1.z - mu, v1.w - mu};
  float vs = 0.f;
#pragma unroll
  for (int i = 0; i < 8; i++) vs += d[i] * d[i];
#pragma unroll
  for (int o = 32; o >= 1; o >>= 1) vs += __shfl_xor(vs, o);
  const float inv = rsqrtf(vs * (1.f / 512.f) + 1e-5f);
  float4 g0 = *(const float4*)(g + lane * 4);
  float4 g1 = *(const float4*)(g + 256 + lane * 4);
  float4 b0 = *(const float4*)(b + lane * 4);
  float4 b1 = *(const float4*)(b + 256 + lane * 4);
  v0.x = d[0] * inv * g0.x + b0.x; v0.y = d[1] * inv * g0.y + b0.y;
  v0.z = d[2] * inv * g0.z + b0.z; v0.w = d[3] * inv * g0.w + b0.w;
  v1.x = d[4] * inv * g1.x + b1.x; v1.y = d[5] * inv * g1.y + b1.y;
  v1.z = d[6] * inv * g1.z + b1.z; v1.w = d[7] * inv * g1.w + b1.w;
  *(float4*)(xr + lane * 4) = v0;
  *(float4*)(xr + 256 + lane * 4) = v1;
}

// --------- dt = softplus(raw + dtb), dA = exp(-dt * exp(Alog)) ---------
__global__ void dtprep_kernel(const float* __restrict__ Z, const float* __restrict__ dtb,
                              const float* __restrict__ Alog,
                              float* __restrict__ dtv, float* __restrict__ dAv)
{
  int idx = blockIdx.x * 256 + threadIdx.x;   // 8192*16
  int row = idx >> 4, hh = idx & 15;
  float raw = Z[(size_t)row * 2320 + 2304 + hh] + dtb[hh];
  float dt = raw > 20.f ? raw : log1pf(expf(raw));
  float dA = expf(-dt * expf(Alog[hh]));
  dtv[idx] = dt;
  dAv[idx] = dA;
}

// ---- depthwise conv(4) + bias + silu. dir=0 causal, dir=1 anti-causal (flip) ----
__global__ void conv_kernel(const float* __restrict__ Z, const float* __restrict__ convw,
                            const float* __restrict__ convb, float* __restrict__ xcv, int dir)
{
  int row = blockIdx.x;                       // b*2048+t
  int c = blockIdx.y * 256 + threadIdx.x;     // 0..1279
  int t = row & 2047;
  size_t bbase = (size_t)(row - t) * 2320;
  float w0 = convw[c * 4 + 0], w1 = convw[c * 4 + 1];
  float w2 = convw[c * 4 + 2], w3 = convw[c * 4 + 3];
  float wv[4] = {w0, w1, w2, w3};
  float acc = convb[c];
#pragma unroll
  for (int k = 0; k < 4; k++) {
    int ts = dir ? (t + 3 - k) : (t - 3 + k);
    if (ts >= 0 && ts < 2048)
      acc += wv[k] * Z[bbase + (size_t)ts * 2320 + 1024 + c];
  }
  xcv[(size_t)row * 1280 + c] = acc * sigf(acc);
}

// ---------------- selective scan: one block per (b,h,p-quarter) ----------------
__global__ __launch_bounds__(256) void scan_kernel(
    const float* __restrict__ xcv, const float* __restrict__ dtv,
    const float* __restrict__ dAv, const float* __restrict__ Dh,
    float* __restrict__ y, int dir)
{
  const int bh = blockIdx.x;              // 0..63
  const int b = bh >> 4, hh = bh & 15;
  const int pbase = blockIdx.y * 16;      // p-quarter
  const int tid = threadIdx.x;
  const int pl = tid >> 4;                // 0..15 local p
  const int q = tid & 15;                 // n-group
  const int n0 = q * 8;
  float s[8];
#pragma unroll
  for (int i = 0; i < 8; i++) s[i] = 0.f;
  const float dh = Dh[hh];

  __shared__ float lx[8][16];
  __shared__ float lB[8][128];
  __shared__ float lC[8][128];
  __shared__ float lA[8];
  __shared__ float lT[8];

  for (int tc = 0; tc < 2048; tc += 8) {
    for (int idx = tid; idx < 544; idx += 256) {
      int stp = idx / 68;
      int off4 = idx - stp * 68;
      int tg = tc + stp;
      int tt = dir ? (2047 - tg) : tg;
      const float* rowp = xcv + (size_t)(b * 2048 + tt) * 1280;
      if (off4 < 4) {
        float4 v = *(const float4*)(rowp + hh * 64 + pbase + off4 * 4);
        *(float4*)&lx[stp][off4 * 4] = v;
      } else if (off4 < 36) {
        int o = (off4 - 4) * 4;
        float4 v = *(const float4*)(rowp + 1024 + o);
        *(float4*)&lB[stp][o] = v;
      } else {
        int o = (off4 - 36) * 4;
        float4 v = *(const float4*)(rowp + 1152 + o);
        *(float4*)&lC[stp][o] = v;
      }
    }
    if (tid < 16) {
      int stp = tid & 7;
      int tg = tc + stp;
      int tt = dir ? (2047 - tg) : tg;
      size_t ridx = (size_t)(b * 2048 + tt) * 16 + hh;
      if (tid < 8) lA[stp] = dAv[ridx];
      else         lT[stp] = dtv[ridx];
    }
    __syncthreads();
#pragma unroll
    for (int j = 0; j < 8; j++) {
      float da = lA[j];
      float xv = lx[j][pl];
      float cm = lT[j] * xv;
      float4 t0 = *(float4*)&lB[j][n0];
      float4 t1 = *(float4*)&lB[j][n0 + 4];
      float4 u0 = *(float4*)&lC[j][n0];
      float4 u1 = *(float4*)&lC[j][n0 + 4];
      float bbv[8] = {t0.x, t0.y, t0.z, t0.w, t1.x, t1.y, t1.z, t1.w};
      float ccv[8] = {u0.x, u0.y, u0.z, u0.w, u1.x, u1.y, u1.z, u1.w};
      float yp = 0.f;
#pragma unroll
      for (int i = 0; i < 8; i++) {
        s[i] = da * s[i] + cm * bbv[i];
        yp += s[i] * ccv[i];
      }
      yp += __shfl_xor(yp, 1);
      yp += __shfl_xor(yp, 2);
      yp += __shfl_xor(yp, 4);
      yp += __shfl_xor(yp, 8);
      if (q == 0) {
        int tg = tc + j;
        int tt = dir ? (2047 - tg) : tg;
        y[(size_t)(b * 2048 + tt) * 1024 + hh * 64 + pbase + pl] = yp + dh * xv;
      }
    }
    __syncthreads();
  }
}

// ------ y = rmsnorm(y * silu(z)) * normw, in place. z = Z[row, 0:1024] ------
__global__ void rms_kernel(float* __restrict__ y, const float* __restrict__ Z,
                           const float* __restrict__ normw)
{
  const int row = blockIdx.x;
  const int lane = threadIdx.x;
  float* yr = y + (size_t)row * 1024;
  const float* zr = Z + (size_t)row * 2320;
  float vals[16];
  float ss = 0.f;
#pragma unroll
  for (int jj = 0; jj < 4; jj++) {
    int off = jj * 256 + lane * 4;
    float4 yv = *(float4*)(yr + off);
    float4 zv = *(const float4*)(zr + off);
    float a0 = yv.x * (zv.x * sigf(zv.x));
    float a1 = yv.y * (zv.y * sigf(zv.y));
    float a2 = yv.z * (zv.z * sigf(zv.z));
    float a3 = yv.w * (zv.w * sigf(zv.w));
    vals[jj * 4 + 0] = a0; vals[jj * 4 + 1] = a1;
    vals[jj * 4 + 2] = a2; vals[jj * 4 + 3] = a3;
    ss += a0 * a0 + a1 * a1 + a2 * a2 + a3 * a3;
  }
#pragma unroll
  for (int o = 32; o >= 1; o >>= 1) ss += __shfl_xor(ss, o);
  const float scale = rsqrtf(ss * (1.f / 1024.f) + 1e-5f);
#pragma unroll
  for (int jj = 0; jj < 4; jj++) {
    int off = jj * 256 + lane * 4;
    float4 nw = *(const float4*)(normw + off);
    float4 o4;
    o4.x = vals[jj * 4 + 0] * scale * nw.x;
    o4.y = vals[jj * 4 + 1] * scale * nw.y;
    o4.z = vals[jj * 4 + 2] * scale * nw.z;
    o4.w = vals[jj * 4 + 3] * scale * nw.w;
    *(float4*)(yr + off) = o4;
  }
}

// ---------------- od = od * silu(h), elementwise over 8192x512 ----------------
__global__ void combine_kernel(float* __restrict__ od, const float* __restrict__ h)
{
  size_t idx = (size_t)blockIdx.x * 256 + threadIdx.x;
  float4 o = ((float4*)od)[idx];
  float4 g = ((const float4*)h)[idx];
  o.x *= g.x * sigf(g.x);
  o.y *= g.y * sigf(g.y);
  o.z *= g.z * sigf(g.z);
  o.w *= g.w * sigf(g.w);
  ((float4*)od)[idx] = o;
}

// ---- out = LN(v)*g+b + shortcut; fn = out / max(||out||,1e-12). 1 wave/row ----
__global__ void lnshort_kernel(const float* __restrict__ v, const float* __restrict__ g,
                               const float* __restrict__ b, const float* __restrict__ shortcut,
                               float* __restrict__ out0, float* __restrict__ fn)
{
  const int row = blockIdx.x;
  const int lane = threadIdx.x;
  size_t base = (size_t)row * 256;
  float4 x = *(const float4*)(v + base + lane * 4);
  float sum = x.x + x.y + x.z + x.w;
#pragma unroll
  for (int o = 32; o >= 1; o >>= 1) sum += __shfl_xor(sum, o);
  const float mu = sum * (1.f / 256.f);
  float d[4] = {x.x - mu, x.y - mu, x.z - mu, x.w - mu};
  float vs = d[0] * d[0] + d[1] * d[1] + d[2] * d[2] + d[3] * d[3];
#pragma unroll
  for (int o = 32; o >= 1; o >>= 1) vs += __shfl_xor(vs, o);
  const float inv = rsqrtf(vs * (1.f / 256.f) + 1e-5f);
  float4 gg = *(const float4*)(g + lane * 4);
  float4 bb = *(const float4*)(b + lane * 4);
  float4 sc = *(const float4*)(shortcut + base + lane * 4);
  float4 o4;
  o4.x = d[0] * inv * gg.x + bb.x + sc.x;
  o4.y = d[1] * inv * gg.y + bb.y + sc.y;
  o4.z = d[2] * inv * gg.z + bb.z + sc.z;
  o4.w = d[3] * inv * gg.w + bb.w + sc.w;
  *(float4*)(out0 + base + lane * 4) = o4;
  float ns = o4.x * o4.x + o4.y * o4.y + o4.z * o4.z + o4.w * o4.w;
#pragma unroll
  for (int o = 32; o >= 1; o >>= 1) ns += __shfl_xor(ns, o);
  const float r = 1.f / fmaxf(sqrtf(ns), 1e-12f);
  o4.x *= r; o4.y *= r; o4.z *= r; o4.w *= r;
  *(float4*)(fn + base + lane * 4) = o4;
}

// ------------- attn[b] = fn[b] @ fn[b]^T  (2048x256 rows, NT GEMM) -------------
__global__ __launch_bounds__(256) void attn_kernel(const float* __restrict__ fn,
                                                   float* __restrict__ attn)
{
  __shared__ float As[32][64];
  __shared__ float Bs2[32][64];
  int bb = blockIdx.z;
  int i0 = blockIdx.x * 64;
  int j0 = blockIdx.y * 64;
  const float* base = fn + (size_t)bb * (2048 * 256);
  int tid = threadIdx.x;
  int tx = tid & 15, ty = tid >> 4;
  float acc[4][4];
#pragma unroll
  for (int i = 0; i < 4; i++)
#pragma unroll
    for (int j = 0; j < 4; j++) acc[i][j] = 0.f;
  for (int k0 = 0; k0 < 256; k0 += 32) {
    for (int l = tid; l < 512; l += 256) {
      int r = l >> 3, kc = (l & 7) * 4;
      float4 av = *(const float4*)(base + (size_t)(i0 + r) * 256 + k0 + kc);
      As[kc + 0][r] = av.x; As[kc + 1][r] = av.y;
      As[kc + 2][r] = av.z; As[kc + 3][r] = av.w;
      float4 bv = *(const float4*)(base + (size_t)(j0 + r) * 256 + k0 + kc);
      Bs2[kc + 0][r] = bv.x; Bs2[kc + 1][r] = bv.y;
      Bs2[kc + 2][r] = bv.z; Bs2[kc + 3][r] = bv.w;
    }
    __syncthreads();
#pragma unroll
    for (int k = 0; k < 32; k++) {
      float4 a4 = *(float4*)&As[k][tx * 4];
      float4 b4 = *(float4*)&Bs2[k][ty * 4];
      float am[4] = {a4.x, a4.y, a4.z, a4.w};
      float bm[4] = {b4.x, b4.y, b4.z, b4.w};
#pragma unroll
      for (int i = 0; i < 4; i++)
#pragma unroll
        for (int j = 0; j < 4; j++) acc[i][j] += am[i] * bm[j];
    }
    __syncthreads();
  }
  size_t ob = (size_t)bb * 2048 * 2048;
#pragma unroll
  for (int i = 0; i < 4; i++) {
    float4 o = make_float4(acc[i][0], acc[i][1], acc[i][2], acc[i][3]);
    *(float4*)(attn + ob + (size_t)(i0 + tx * 4 + i) * 2048 + j0 + ty * 4) = o;
  }
}

extern "C" void kernel_launch(void* const* d_in, const int* in_sizes, int n_in,
                              void* d_out, int out_size, void* d_ws, size_t ws_size,
                              hipStream_t stream)
{
  (void)in_sizes; (void)n_in; (void)out_size; (void)ws_size;
  const float* x        = (const float*)d_in[0];
  const float* Wp       = (const float*)d_in[1];
  const float* bp       = (const float*)d_in[2];
  const float* Wpre     = (const float*)d_in[3];
  const float* bpre     = (const float*)d_in[4];
  const float* lnpre_g  = (const float*)d_in[5];
  const float* lnpre_b  = (const float*)d_in[6];
  const float* Wpost    = (const float*)d_in[7];
  const float* bpost    = (const float*)d_in[8];
  const float* lnpost_g = (const float*)d_in[9];
  const float* lnpost_b = (const float*)d_in[10];

  // workspace layout (floats); total = 42,336,256 floats = 169.3 MB
  float* ws   = (float*)d_ws;
  float* xc   = ws;                   // 8192x256  shortcut
  float* hbuf = xc + 2097152;         // 8192x512  pre -> h (in-place LN)
  float* Zb   = hbuf + 4194304;       // 8192x2320 zxbcdt (reused per dir)
  float* ybuf = Zb + 19005440;        // 8192x1024 scan out (reused per dir)
  float* od   = ybuf + 8388608;       // 8192x512  out_f + out_b
  float* vbuf = od + 4194304;         // 8192x256
  float* fnb  = vbuf + 2097152;       // 8192x256
  float* dtv  = fnb + 2097152;        // 8192x16
  float* dAv  = dtv + 131072;         // 8192x16

  float* out0 = (float*)d_out;        // 4x2048x256
  float* attn = out0 + 2097152;       // 4x2048x2048
  float* xcv  = attn;                 // conv scratch overlays attn (written last)

  // x_ = gather(x) @ Wp + bp   -> shortcut
  gemm_kernel<true, true, false><<<dim3(128, 4), 256, 0, stream>>>(x, Wp, bp, xc, 8192, 256, 768);
  // pre = x_ @ Wpre + bpre ; h = LN(pre) in place
  gemm_kernel<false, true, false><<<dim3(128, 8), 256, 0, stream>>>(xc, Wpre, bpre, hbuf, 8192, 512, 256);
  ln512_kernel<<<8192, 64, 0, stream>>>(hbuf, lnpre_g, lnpre_b);

  for (int dir = 0; dir < 2; dir++) {
    const float* Win   = (const float*)d_in[11 + dir * 8];
    const float* convw = (const float*)d_in[12 + dir * 8];
    const float* convb = (const float*)d_in[13 + dir * 8];
    const float* dtb   = (const float*)d_in[14 + dir * 8];
    const float* Alog  = (const float*)d_in[15 + dir * 8];
    const float* Dh    = (const float*)d_in[16 + dir * 8];
    const float* normw = (const float*)d_in[17 + dir * 8];
    const float* Wout  = (const float*)d_in[18 + dir * 8];

    gemm_kernel<false, false, false><<<dim3(128, 37), 256, 0, stream>>>(hbuf, Win, nullptr, Zb, 8192, 2320, 512);
    dtprep_kernel<<<512, 256, 0, stream>>>(Zb, dtb, Alog, dtv, dAv);
    conv_kernel<<<dim3(8192, 5), 256, 0, stream>>>(Zb, convw, convb, xcv, dir);
    scan_kernel<<<dim3(64, 4), 256, 0, stream>>>(xcv, dtv, dAv, Dh, ybuf, dir);
    rms_kernel<<<8192, 64, 0, stream>>>(ybuf, Zb, normw);
    if (dir == 0)
      gemm_kernel<false, false, false><<<dim3(128, 8), 256, 0, stream>>>(ybuf, Wout, nullptr, od, 8192, 512, 1024);
    else
      gemm_kernel<false, false, true><<<dim3(128, 8), 256, 0, stream>>>(ybuf, Wout, nullptr, od, 8192, 512, 1024);
  }

  // u = (out_f + out_b) * silu(h), then post-proj, post-LN + shortcut, fn, attn
  combine_kernel<<<4096, 256, 0, stream>>>(od, hbuf);
  gemm_kernel<false, true, false><<<dim3(128, 4), 256, 0, stream>>>(od, Wpost, bpost, vbuf, 8192, 256, 512);
  lnshort_kernel<<<8192, 64, 0, stream>>>(vbuf, lnpost_g, lnpost_b, xc, out0, fnb);
  attn_kernel<<<dim3(32, 32, 4), 256, 0, stream>>>(fnb, attn);
}

// Round 2
// 1891.360 us; speedup vs baseline: 1.9206x; 1.9206x over previous
//
#include <hip/hip_runtime.h>
#include <math.h>

__device__ __forceinline__ float sigf(float v) { return 1.f / (1.f + __expf(-v)); }

// ---------------- GEMM: C[M,N] = A[M,K] @ W[K,N] (+bias) (+=C) ----------------
template<bool GATHER, bool BIAS, bool ACC>
__global__ __launch_bounds__(256) void gemm_kernel(
    const float* __restrict__ A, const float* __restrict__ W,
    const float* __restrict__ bias, float* __restrict__ C,
    int M, int N, int K)
{
  __shared__ float As[16][64];
  __shared__ float Bs[16][64];
  const int tid = threadIdx.x;
  const int m0 = blockIdx.x * 64;
  const int n0 = blockIdx.y * 64;
  const int tx = tid & 15;
  const int ty = tid >> 4;
  float acc[4][4];
#pragma unroll
  for (int i = 0; i < 4; i++)
#pragma unroll
    for (int j = 0; j < 4; j++) acc[i][j] = 0.f;

  const int ar  = tid >> 2;
  const int akc = (tid & 3) * 4;
  const int bkr = tid >> 4;
  const int bnc = (tid & 15) * 4;

  for (int k0 = 0; k0 < K; k0 += 16) {
    float4 av;
    if (GATHER) {
      int m = m0 + ar; int bb = m >> 11; int t = m & 2047;
      int kk = k0 + akc; int s = kk >> 8; int d = kk & 255;
      av = *(const float4*)(A + ((size_t)((bb * 3 + s) * 2048 + t) << 8) + d);
    } else {
      av = *(const float4*)(A + (size_t)(m0 + ar) * K + (k0 + akc));
    }
    As[akc + 0][ar] = av.x;
    As[akc + 1][ar] = av.y;
    As[akc + 2][ar] = av.z;
    As[akc + 3][ar] = av.w;

    float4 bv = make_float4(0.f, 0.f, 0.f, 0.f);
    int nn = n0 + bnc;
    if (nn + 3 < N) bv = *(const float4*)(W + (size_t)(k0 + bkr) * N + nn);
    *(float4*)&Bs[bkr][bnc] = bv;
    __syncthreads();
#pragma unroll
    for (int k = 0; k < 16; k++) {
      float4 a4 = *(float4*)&As[k][tx * 4];
      float4 b4 = *(float4*)&Bs[k][ty * 4];
      float am[4] = {a4.x, a4.y, a4.z, a4.w};
      float bm[4] = {b4.x, b4.y, b4.z, b4.w};
#pragma unroll
      for (int i = 0; i < 4; i++)
#pragma unroll
        for (int j = 0; j < 4; j++) acc[i][j] += am[i] * bm[j];
    }
    __syncthreads();
  }
  const int nc = n0 + ty * 4;
  if (nc + 3 < N) {
    float4 b4 = make_float4(0.f, 0.f, 0.f, 0.f);
    if (BIAS) b4 = *(const float4*)(bias + nc);
#pragma unroll
    for (int i = 0; i < 4; i++) {
      int m = m0 + tx * 4 + i;
      float* cp = C + (size_t)m * N + nc;
      float4 o;
      o.x = acc[i][0] + b4.x;
      o.y = acc[i][1] + b4.y;
      o.z = acc[i][2] + b4.z;
      o.w = acc[i][3] + b4.w;
      if (ACC) {
        float4 p = *(float4*)cp;
        o.x += p.x; o.y += p.y; o.z += p.z; o.w += p.w;
      }
      *(float4*)cp = o;
    }
  }
}

// ---------------- LayerNorm over 512, in place ----------------
__global__ void ln512_kernel(float* __restrict__ xio, const float* __restrict__ g,
                             const float* __restrict__ b)
{
  const int row = blockIdx.x;
  const int lane = threadIdx.x;
  float* xr = xio + (size_t)row * 512;
  float4 v0 = *(float4*)(xr + lane * 4);
  float4 v1 = *(float4*)(xr + 256 + lane * 4);
  float sum = v0.x + v0.y + v0.z + v0.w + v1.x + v1.y + v1.z + v1.w;
#pragma unroll
  for (int o = 32; o >= 1; o >>= 1) sum += __shfl_xor(sum, o);
  const float mu = sum * (1.f / 512.f);
  float d[8] = {v0.x - mu, v0.y - mu, v0.z - mu, v0.w - mu,
                v1.x - mu, v1.y - mu, v1.z - mu, v1.w - mu};
  float vs = 0.f;
#pragma unroll
  for (int i = 0; i < 8; i++) vs += d[i] * d[i];
#pragma unroll
  for (int o = 32; o >= 1; o >>= 1) vs += __shfl_xor(vs, o);
  const float inv = rsqrtf(vs * (1.f / 512.f) + 1e-5f);
  float4 g0 = *(const float4*)(g + lane * 4);
  float4 g1 = *(const float4*)(g + 256 + lane * 4);
  float4 b0 = *(const float4*)(b + lane * 4);
  float4 b1 = *(const float4*)(b + 256 + lane * 4);
  v0.x = d[0] * inv * g0.x + b0.x; v0.y = d[1] * inv * g0.y + b0.y;
  v0.z = d[2] * inv * g0.z + b0.z; v0.w = d[3] * inv * g0.w + b0.w;
  v1.x = d[4] * inv * g1.x + b1.x; v1.y = d[5] * inv * g1.y + b1.y;
  v1.z = d[6] * inv * g1.z + b1.z; v1.w = d[7] * inv * g1.w + b1.w;
  *(float4*)(xr + lane * 4) = v0;
  *(float4*)(xr + 256 + lane * 4) = v1;
}

// --------- dt = softplus(raw + dtb), logdA = -dt * exp(Alog) ---------
__global__ void dtprep_kernel(const float* __restrict__ Z, const float* __restrict__ dtb,
                              const float* __restrict__ Alog,
                              float* __restrict__ dtv, float* __restrict__ ldA)
{
  int idx = blockIdx.x * 256 + threadIdx.x;   // 8192*16
  int row = idx >> 4, hh = idx & 15;
  float raw = Z[(size_t)row * 2320 + 2304 + hh] + dtb[hh];
  float dt = raw > 20.f ? raw : log1pf(expf(raw));
  dtv[idx] = dt;
  ldA[idx] = -dt * expf(Alog[hh]);
}

// ---- depthwise conv(4) + bias + silu. dir=0 causal, dir=1 anti-causal ----
__global__ void conv_kernel(const float* __restrict__ Z, const float* __restrict__ convw,
                            const float* __restrict__ convb, float* __restrict__ xcv, int dir)
{
  int row = blockIdx.x;
  int c = blockIdx.y * 256 + threadIdx.x;
  int t = row & 2047;
  size_t bbase = (size_t)(row - t) * 2320;
  float wv[4] = {convw[c * 4 + 0], convw[c * 4 + 1], convw[c * 4 + 2], convw[c * 4 + 3]};
  float acc = convb[c];
#pragma unroll
  for (int k = 0; k < 4; k++) {
    int ts = dir ? (t + 3 - k) : (t - 3 + k);
    if (ts >= 0 && ts < 2048)
      acc += wv[k] * Z[bbase + (size_t)ts * 2320 + 1024 + c];
  }
  xcv[(size_t)row * 1280 + c] = acc * sigf(acc);
}

// ============ chunked SSD scan, Lc=64, 32 chunks ============
// chunk_state: S[p][n] = sum_s exp(Ltot - L_s) dt_s x_s[p] B_s[n]; P = exp(Ltot)
__global__ __launch_bounds__(256) void chunk_state_kernel(
    const float* __restrict__ xcv, const float* __restrict__ dtv,
    const float* __restrict__ ldA, float* __restrict__ Sbuf,
    float* __restrict__ Pbuf, int dir)
{
  const int bh = blockIdx.x, ck = blockIdx.y;
  const int b = bh >> 4, h = bh & 15;
  const int tid = threadIdx.x;
  __shared__ float sx[64][64];
  __shared__ float sB[64][128];
  __shared__ float sw[64];

  if (tid < 64) {
    int tg = ck * 64 + tid;
    int tt = dir ? 2047 - tg : tg;
    size_t r = (size_t)(b * 2048 + tt) * 16 + h;
    float v = ldA[r];
#pragma unroll
    for (int o = 1; o < 64; o <<= 1) { float u = __shfl_up(v, o); if (tid >= o) v += u; }
    float tot = __shfl(v, 63);
    sw[tid] = __expf(tot - v) * dtv[r];
    if (tid == 63) Pbuf[bh * 32 + ck] = __expf(tot);
  }
  for (int i4 = tid; i4 < 1024; i4 += 256) {
    int t = i4 >> 4, c4 = i4 & 15;
    int tg = ck * 64 + t; int tt = dir ? 2047 - tg : tg;
    *(float4*)&sx[t][c4 * 4] =
        *(const float4*)(xcv + (size_t)(b * 2048 + tt) * 1280 + h * 64 + c4 * 4);
  }
  for (int i4 = tid; i4 < 2048; i4 += 256) {
    int t = i4 >> 5, c4 = i4 & 31;
    int tg = ck * 64 + t; int tt = dir ? 2047 - tg : tg;
    *(float4*)&sB[t][c4 * 4] =
        *(const float4*)(xcv + (size_t)(b * 2048 + tt) * 1280 + 1024 + c4 * 4);
  }
  __syncthreads();
  const int p0 = (tid >> 4) * 4;
  const int n0 = (tid & 15) * 4;
  float acc[4][8];
#pragma unroll
  for (int i = 0; i < 4; i++)
#pragma unroll
    for (int j = 0; j < 8; j++) acc[i][j] = 0.f;
  for (int s = 0; s < 64; s++) {
    float w = sw[s];
    float4 xv = *(float4*)&sx[s][p0];
    float4 b0v = *(float4*)&sB[s][n0];
    float4 b1v = *(float4*)&sB[s][n0 + 64];
    float xw[4] = {xv.x * w, xv.y * w, xv.z * w, xv.w * w};
    float bb[8] = {b0v.x, b0v.y, b0v.z, b0v.w, b1v.x, b1v.y, b1v.z, b1v.w};
#pragma unroll
    for (int i = 0; i < 4; i++)
#pragma unroll
      for (int j = 0; j < 8; j++) acc[i][j] += xw[i] * bb[j];
  }
  float* Sp = Sbuf + ((size_t)(bh * 32 + ck) << 13);
#pragma unroll
  for (int i = 0; i < 4; i++) {
    *(float4*)(Sp + (p0 + i) * 128 + n0) = make_float4(acc[i][0], acc[i][1], acc[i][2], acc[i][3]);
    *(float4*)(Sp + (p0 + i) * 128 + n0 + 64) = make_float4(acc[i][4], acc[i][5], acc[i][6], acc[i][7]);
  }
}

// chunk_scan: in place, Sbuf[ck] <- state entering chunk ck
__global__ void chunk_scan_kernel(float* __restrict__ Sbuf, const float* __restrict__ Pbuf)
{
  int idx = blockIdx.x * 256 + threadIdx.x;
  int bh = idx >> 13, elem = idx & 8191;
  float hh = 0.f;
  for (int ck = 0; ck < 32; ck++) {
    size_t off = ((size_t)(bh * 32 + ck) << 13) + elem;
    float s = Sbuf[off];
    float P = Pbuf[bh * 32 + ck];
    Sbuf[off] = hh;
    hh = P * hh + s;
  }
}

// chunk_out: y = M@x + exp(L_t) * (C @ Hpre^T) + Dh*x
__global__ __launch_bounds__(256) void chunk_out_kernel(
    const float* __restrict__ xcv, const float* __restrict__ dtv,
    const float* __restrict__ ldA, const float* __restrict__ Sbuf,
    const float* __restrict__ Dh, float* __restrict__ y, int dir)
{
  extern __shared__ float smem[];
  float (*sCt)[64] = (float(*)[64])smem;             // [128][64] k-major C
  float (*sBt)[64] = (float(*)[64])(smem + 8192);    // [128][64] k-major B, later Hpre^T
  float (*sx)[64]  = (float(*)[64])(smem + 16384);   // [64][64]
  float (*sM)[64]  = (float(*)[64])(smem + 20480);   // [64][64]  stored [s][t]
  float* sL  = smem + 24576;
  float* sdt = smem + 24640;

  const int bh = blockIdx.x, ck = blockIdx.y;
  const int b = bh >> 4, h = bh & 15;
  const int tid = threadIdx.x;

  if (tid < 64) {
    int tg = ck * 64 + tid;
    int tt = dir ? 2047 - tg : tg;
    size_t r = (size_t)(b * 2048 + tt) * 16 + h;
    float v = ldA[r];
#pragma unroll
    for (int o = 1; o < 64; o <<= 1) { float u = __shfl_up(v, o); if (tid >= o) v += u; }
    sL[tid] = v;
    sdt[tid] = dtv[r];
  }
  // stage C, B transposed (k-major), x natural
  for (int i4 = tid; i4 < 2048; i4 += 256) {
    int t = i4 >> 5, c4 = i4 & 31;
    int tg = ck * 64 + t; int tt = dir ? 2047 - tg : tg;
    const float* rp = xcv + (size_t)(b * 2048 + tt) * 1280;
    float4 bv = *(const float4*)(rp + 1024 + c4 * 4);
    sBt[c4 * 4 + 0][t] = bv.x; sBt[c4 * 4 + 1][t] = bv.y;
    sBt[c4 * 4 + 2][t] = bv.z; sBt[c4 * 4 + 3][t] = bv.w;
    float4 cv = *(const float4*)(rp + 1152 + c4 * 4);
    sCt[c4 * 4 + 0][t] = cv.x; sCt[c4 * 4 + 1][t] = cv.y;
    sCt[c4 * 4 + 2][t] = cv.z; sCt[c4 * 4 + 3][t] = cv.w;
  }
  for (int i4 = tid; i4 < 1024; i4 += 256) {
    int t = i4 >> 4, c4 = i4 & 15;
    int tg = ck * 64 + t; int tt = dir ? 2047 - tg : tg;
    *(float4*)&sx[t][c4 * 4] =
        *(const float4*)(xcv + (size_t)(b * 2048 + tt) * 1280 + h * 64 + c4 * 4);
  }
  __syncthreads();

  const int i0 = (tid >> 4) * 4;   // t tile
  const int j0 = (tid & 15) * 4;   // s tile (scores) / p tile (output)

  // scores
  float acc[4][4];
#pragma unroll
  for (int i = 0; i < 4; i++)
#pragma unroll
    for (int j = 0; j < 4; j++) acc[i][j] = 0.f;
  for (int n = 0; n < 128; n++) {
    float4 cv = *(float4*)&sCt[n][i0];
    float4 bv = *(float4*)&sBt[n][j0];
    float cm[4] = {cv.x, cv.y, cv.z, cv.w};
    float bm[4] = {bv.x, bv.y, bv.z, bv.w};
#pragma unroll
    for (int i = 0; i < 4; i++)
#pragma unroll
      for (int j = 0; j < 4; j++) acc[i][j] += cm[i] * bm[j];
  }
#pragma unroll
  for (int ti = 0; ti < 4; ti++)
#pragma unroll
    for (int sj = 0; sj < 4; sj++) {
      int t = i0 + ti, s = j0 + sj;
      float v = (t >= s) ? acc[ti][sj] * __expf(sL[t] - sL[s]) * sdt[s] : 0.f;
      sM[s][t] = v;
    }
  __syncthreads();

  // prefetch Hpre while computing intra
  const float* Hp = Sbuf + ((size_t)(bh * 32 + ck) << 13);
  float4 hreg[8];
#pragma unroll
  for (int k = 0; k < 8; k++) {
    int i4 = tid + k * 256;
    hreg[k] = *(const float4*)(Hp + i4 * 4);
  }
  float yacc[4][4];
#pragma unroll
  for (int i = 0; i < 4; i++)
#pragma unroll
    for (int j = 0; j < 4; j++) yacc[i][j] = 0.f;
  for (int s = 0; s < 64; s++) {
    float4 mv = *(float4*)&sM[s][i0];
    float4 xv = *(float4*)&sx[s][j0];
    float mm[4] = {mv.x, mv.y, mv.z, mv.w};
    float xm[4] = {xv.x, xv.y, xv.z, xv.w};
#pragma unroll
    for (int i = 0; i < 4; i++)
#pragma unroll
      for (int j = 0; j < 4; j++) yacc[i][j] += mm[i] * xm[j];
  }
  __syncthreads();   // everyone done reading sBt as B
#pragma unroll
  for (int k = 0; k < 8; k++) {
    int i4 = tid + k * 256;
    int p = i4 >> 5, c4 = i4 & 31;
    sBt[c4 * 4 + 0][p] = hreg[k].x; sBt[c4 * 4 + 1][p] = hreg[k].y;
    sBt[c4 * 4 + 2][p] = hreg[k].z; sBt[c4 * 4 + 3][p] = hreg[k].w;
  }
  __syncthreads();

  // inter: acc2[t][p] = sum_n C[t][n] * Hpre[p][n]
  float acc2[4][4];
#pragma unroll
  for (int i = 0; i < 4; i++)
#pragma unroll
    for (int j = 0; j < 4; j++) acc2[i][j] = 0.f;
  for (int n = 0; n < 128; n++) {
    float4 cv = *(float4*)&sCt[n][i0];
    float4 hv = *(float4*)&sBt[n][j0];
    float cm[4] = {cv.x, cv.y, cv.z, cv.w};
    float hm[4] = {hv.x, hv.y, hv.z, hv.w};
#pragma unroll
    for (int i = 0; i < 4; i++)
#pragma unroll
      for (int j = 0; j < 4; j++) acc2[i][j] += cm[i] * hm[j];
  }
  const float dh = Dh[h];
#pragma unroll
  for (int ti = 0; ti < 4; ti++) {
    int t = i0 + ti;
    float e = __expf(sL[t]);
    int tg = ck * 64 + t; int tt = dir ? 2047 - tg : tg;
    float4 o;
    o.x = yacc[ti][0] + e * acc2[ti][0] + dh * sx[t][j0 + 0];
    o.y = yacc[ti][1] + e * acc2[ti][1] + dh * sx[t][j0 + 1];
    o.z = yacc[ti][2] + e * acc2[ti][2] + dh * sx[t][j0 + 2];
    o.w = yacc[ti][3] + e * acc2[ti][3] + dh * sx[t][j0 + 3];
    *(float4*)(y + (size_t)(b * 2048 + tt) * 1024 + h * 64 + j0) = o;
  }
}

// ------ y = rmsnorm(y * silu(z)) * normw, in place ------
__global__ void rms_kernel(float* __restrict__ y, const float* __restrict__ Z,
                           const float* __restrict__ normw)
{
  const int row = blockIdx.x;
  const int lane = threadIdx.x;
  float* yr = y + (size_t)row * 1024;
  const float* zr = Z + (size_t)row * 2320;
  float vals[16];
  float ss = 0.f;
#pragma unroll
  for (int jj = 0; jj < 4; jj++) {
    int off = jj * 256 + lane * 4;
    float4 yv = *(float4*)(yr + off);
    float4 zv = *(const float4*)(zr + off);
    float a0 = yv.x * (zv.x * sigf(zv.x));
    float a1 = yv.y * (zv.y * sigf(zv.y));
    float a2 = yv.z * (zv.z * sigf(zv.z));
    float a3 = yv.w * (zv.w * sigf(zv.w));
    vals[jj * 4 + 0] = a0; vals[jj * 4 + 1] = a1;
    vals[jj * 4 + 2] = a2; vals[jj * 4 + 3] = a3;
    ss += a0 * a0 + a1 * a1 + a2 * a2 + a3 * a3;
  }
#pragma unroll
  for (int o = 32; o >= 1; o >>= 1) ss += __shfl_xor(ss, o);
  const float scale = rsqrtf(ss * (1.f / 1024.f) + 1e-5f);
#pragma unroll
  for (int jj = 0; jj < 4; jj++) {
    int off = jj * 256 + lane * 4;
    float4 nw = *(const float4*)(normw + off);
    float4 o4;
    o4.x = vals[jj * 4 + 0] * scale * nw.x;
    o4.y = vals[jj * 4 + 1] * scale * nw.y;
    o4.z = vals[jj * 4 + 2] * scale * nw.z;
    o4.w = vals[jj * 4 + 3] * scale * nw.w;
    *(float4*)(yr + off) = o4;
  }
}

__global__ void combine_kernel(float* __restrict__ od, const float* __restrict__ h)
{
  size_t idx = (size_t)blockIdx.x * 256 + threadIdx.x;
  float4 o = ((float4*)od)[idx];
  float4 g = ((const float4*)h)[idx];
  o.x *= g.x * sigf(g.x);
  o.y *= g.y * sigf(g.y);
  o.z *= g.z * sigf(g.z);
  o.w *= g.w * sigf(g.w);
  ((float4*)od)[idx] = o;
}

__global__ void lnshort_kernel(const float* __restrict__ v, const float* __restrict__ g,
                               const float* __restrict__ b, const float* __restrict__ shortcut,
                               float* __restrict__ out0, float* __restrict__ fn)
{
  const int row = blockIdx.x;
  const int lane = threadIdx.x;
  size_t base = (size_t)row * 256;
  float4 x = *(const float4*)(v + base + lane * 4);
  float sum = x.x + x.y + x.z + x.w;
#pragma unroll
  for (int o = 32; o >= 1; o >>= 1) sum += __shfl_xor(sum, o);
  const float mu = sum * (1.f / 256.f);
  float d[4] = {x.x - mu, x.y - mu, x.z - mu, x.w - mu};
  float vs = d[0] * d[0] + d[1] * d[1] + d[2] * d[2] + d[3] * d[3];
#pragma unroll
  for (int o = 32; o >= 1; o >>= 1) vs += __shfl_xor(vs, o);
  const float inv = rsqrtf(vs * (1.f / 256.f) + 1e-5f);
  float4 gg = *(const float4*)(g + lane * 4);
  float4 bb = *(const float4*)(b + lane * 4);
  float4 sc = *(const float4*)(shortcut + base + lane * 4);
  float4 o4;
  o4.x = d[0] * inv * gg.x + bb.x + sc.x;
  o4.y = d[1] * inv * gg.y + bb.y + sc.y;
  o4.z = d[2] * inv * gg.z + bb.z + sc.z;
  o4.w = d[3] * inv * gg.w + bb.w + sc.w;
  *(float4*)(out0 + base + lane * 4) = o4;
  float ns = o4.x * o4.x + o4.y * o4.y + o4.z * o4.z + o4.w * o4.w;
#pragma unroll
  for (int o = 32; o >= 1; o >>= 1) ns += __shfl_xor(ns, o);
  const float r = 1.f / fmaxf(sqrtf(ns), 1e-12f);
  o4.x *= r; o4.y *= r; o4.z *= r; o4.w *= r;
  *(float4*)(fn + base + lane * 4) = o4;
}

__global__ __launch_bounds__(256) void attn_kernel(const float* __restrict__ fn,
                                                   float* __restrict__ attn)
{
  __shared__ float As[32][64];
  __shared__ float Bs2[32][64];
  int bb = blockIdx.z;
  int i0 = blockIdx.x * 64;
  int j0 = blockIdx.y * 64;
  const float* base = fn + (size_t)bb * (2048 * 256);
  int tid = threadIdx.x;
  int tx = tid & 15, ty = tid >> 4;
  float acc[4][4];
#pragma unroll
  for (int i = 0; i < 4; i++)
#pragma unroll
    for (int j = 0; j < 4; j++) acc[i][j] = 0.f;
  for (int k0 = 0; k0 < 256; k0 += 32) {
    for (int l = tid; l < 512; l += 256) {
      int r = l >> 3, kc = (l & 7) * 4;
      float4 av = *(const float4*)(base + (size_t)(i0 + r) * 256 + k0 + kc);
      As[kc + 0][r] = av.x; As[kc + 1][r] = av.y;
      As[kc + 2][r] = av.z; As[kc + 3][r] = av.w;
      float4 bv = *(const float4*)(base + (size_t)(j0 + r) * 256 + k0 + kc);
      Bs2[kc + 0][r] = bv.x; Bs2[kc + 1][r] = bv.y;
      Bs2[kc + 2][r] = bv.z; Bs2[kc + 3][r] = bv.w;
    }
    __syncthreads();
#pragma unroll
    for (int k = 0; k < 32; k++) {
      float4 a4 = *(float4*)&As[k][tx * 4];
      float4 b4 = *(float4*)&Bs2[k][ty * 4];
      float am[4] = {a4.x, a4.y, a4.z, a4.w};
      float bm[4] = {b4.x, b4.y, b4.z, b4.w};
#pragma unroll
      for (int i = 0; i < 4; i++)
#pragma unroll
        for (int j = 0; j < 4; j++) acc[i][j] += am[i] * bm[j];
    }
    __syncthreads();
  }
  size_t ob = (size_t)bb * 2048 * 2048;
#pragma unroll
  for (int i = 0; i < 4; i++) {
    float4 o = make_float4(acc[i][0], acc[i][1], acc[i][2], acc[i][3]);
    *(float4*)(attn + ob + (size_t)(i0 + tx * 4 + i) * 2048 + j0 + ty * 4) = o;
  }
}

extern "C" void kernel_launch(void* const* d_in, const int* in_sizes, int n_in,
                              void* d_out, int out_size, void* d_ws, size_t ws_size,
                              hipStream_t stream)
{
  (void)in_sizes; (void)n_in; (void)out_size; (void)ws_size;
  const float* x        = (const float*)d_in[0];
  const float* Wp       = (const float*)d_in[1];
  const float* bp       = (const float*)d_in[2];
  const float* Wpre     = (const float*)d_in[3];
  const float* bpre     = (const float*)d_in[4];
  const float* lnpre_g  = (const float*)d_in[5];
  const float* lnpre_b  = (const float*)d_in[6];
  const float* Wpost    = (const float*)d_in[7];
  const float* bpost    = (const float*)d_in[8];
  const float* lnpost_g = (const float*)d_in[9];
  const float* lnpost_b = (const float*)d_in[10];

  // ws layout (floats), total 48,629,760 = 185.5 MiB
  float* ws   = (float*)d_ws;
  float* xc   = ws;                   // 8192x256
  float* hbuf = xc + 2097152;         // 8192x512
  float* Zb   = hbuf + 4194304;       // 8192x2320
  float* ybuf = Zb + 19005440;        // 8192x1024
  float* od   = ybuf + 8388608;       // 8192x512
  float* dtv  = od + 4194304;         // 8192x16
  float* ldA  = dtv + 131072;         // 8192x16
  float* Pbuf = ldA + 131072;         // 2048
  float* xcv  = Pbuf + 2048;          // 8192x1280
  float* vbuf = ybuf;                 // overlay (ybuf dead by then)
  float* fnb  = ybuf + 2097152;       // overlay

  float* out0 = (float*)d_out;        // 4x2048x256
  float* attn = out0 + 2097152;       // 4x2048x2048
  float* Sbuf = attn;                 // 64*32*8192 floats == attn region exactly

  gemm_kernel<true, true, false><<<dim3(128, 4), 256, 0, stream>>>(x, Wp, bp, xc, 8192, 256, 768);
  gemm_kernel<false, true, false><<<dim3(128, 8), 256, 0, stream>>>(xc, Wpre, bpre, hbuf, 8192, 512, 256);
  ln512_kernel<<<8192, 64, 0, stream>>>(hbuf, lnpre_g, lnpre_b);

  for (int dir = 0; dir < 2; dir++) {
    const float* Win   = (const float*)d_in[11 + dir * 8];
    const float* convw = (const float*)d_in[12 + dir * 8];
    const float* convb = (const float*)d_in[13 + dir * 8];
    const float* dtb   = (const float*)d_in[14 + dir * 8];
    const float* Alog  = (const float*)d_in[15 + dir * 8];
    const float* Dh    = (const float*)d_in[16 + dir * 8];
    const float* normw = (const float*)d_in[17 + dir * 8];
    const float* Wout  = (const float*)d_in[18 + dir * 8];

    gemm_kernel<false, false, false><<<dim3(128, 37), 256, 0, stream>>>(hbuf, Win, nullptr, Zb, 8192, 2320, 512);
    dtprep_kernel<<<512, 256, 0, stream>>>(Zb, dtb, Alog, dtv, ldA);
    conv_kernel<<<dim3(8192, 5), 256, 0, stream>>>(Zb, convw, convb, xcv, dir);
    chunk_state_kernel<<<dim3(64, 32), 256, 0, stream>>>(xcv, dtv, ldA, Sbuf, Pbuf, dir);
    chunk_scan_kernel<<<2048, 256, 0, stream>>>(Sbuf, Pbuf);
    chunk_out_kernel<<<dim3(64, 32), 256, 98816, stream>>>(xcv, dtv, ldA, Sbuf, Dh, ybuf, dir);
    rms_kernel<<<8192, 64, 0, stream>>>(ybuf, Zb, normw);
    if (dir == 0)
      gemm_kernel<false, false, false><<<dim3(128, 8), 256, 0, stream>>>(ybuf, Wout, nullptr, od, 8192, 512, 1024);
    else
      gemm_kernel<false, false, true><<<dim3(128, 8), 256, 0, stream>>>(ybuf, Wout, nullptr, od, 8192, 512, 1024);
  }

  combine_kernel<<<4096, 256, 0, stream>>>(od, hbuf);
  gemm_kernel<false, true, false><<<dim3(128, 4), 256, 0, stream>>>(od, Wpost, bpost, vbuf, 8192, 256, 512);
  lnshort_kernel<<<8192, 64, 0, stream>>>(vbuf, lnpost_g, lnpost_b, xc, out0, fnb);
  attn_kernel<<<dim3(32, 32, 4), 256, 0, stream>>>(fnb, attn);
}

// Round 4
// 1035.353 us; speedup vs baseline: 3.5085x; 1.8268x over previous
//
#include <hip/hip_runtime.h>
#include <math.h>

__device__ __forceinline__ float sigf(float v) { return 1.f / (1.f + __expf(-v)); }

__device__ __forceinline__ short f2bf(float f) {
  unsigned int u = __builtin_bit_cast(unsigned int, f);
  unsigned int r = (u + 0x7fffu + ((u >> 16) & 1u)) >> 16;
  return (short)r;
}
__device__ __forceinline__ float bf2f(short s) {
  unsigned int u = ((unsigned int)(unsigned short)s) << 16;
  return __builtin_bit_cast(float, u);
}

typedef short bf16x8 __attribute__((ext_vector_type(8)));
typedef float f32x4 __attribute__((ext_vector_type(4)));

__device__ __forceinline__ void async16(const short* g, short* l) {
  __builtin_amdgcn_global_load_lds(
      (const __attribute__((address_space(1))) unsigned int*)g,
      (__attribute__((address_space(3))) unsigned int*)l, 16, 0, 0);
}

// ============ bf16 MFMA GEMM: C[M,N] += A[M,K] @ Bt[N,K]^T ============
// 128x128 tile, BK=32, 256 threads (4 waves, 2x2), 16 MFMA 16x16x32 per wave/step.
template<bool BIAS, bool ACC>
__global__ __launch_bounds__(256) void gemm16_kernel(
    const short* __restrict__ A, const short* __restrict__ Bt,
    const float* __restrict__ bias, float* __restrict__ C,
    int M, int N, int K, int ldc,
    long long sAb, long long sBb, long long sCb)
{
  __shared__ short smA[128 * 32];
  __shared__ short smB[128 * 32];
  const int tid = threadIdx.x;
  const int wave = tid >> 6;
  const int lane = tid & 63;
  const int m0 = blockIdx.x * 128;
  const int n0 = blockIdx.y * 128;
  const int bz = blockIdx.z;
  const short* Ab = A + (size_t)bz * sAb;
  const short* Bb = Bt + (size_t)bz * sBb;
  float* Cb = C + (size_t)bz * sCb;

  f32x4 acc[4][4] = {};

  const int isB = wave >> 1;        // waves 0,1 stage A; 2,3 stage B
  const int half = wave & 1;        // which 64-row half
  const short* gsrc = isB ? Bb : Ab;
  short* ldsbase = isB ? smB : smA;
  const int tile_r0 = isB ? n0 : m0;
  const int lrow = lane >> 2;       // 0..15 row within 16-row chunk
  const int lk = (lane & 3) * 8;    // k offset

  const int wm = wave >> 1, wn = wave & 1;

  for (int k0 = 0; k0 < K; k0 += 32) {
#pragma unroll
    for (int c = 0; c < 4; c++) {
      int row = half * 64 + c * 16 + lrow;
      const short* g = gsrc + (size_t)(tile_r0 + row) * K + k0 + lk;
      short* l = ldsbase + (half * 64 + c * 16) * 32;   // wave-uniform base
      async16(g, l);
    }
    __syncthreads();
    bf16x8 af[4], bfr[4];
#pragma unroll
    for (int mt = 0; mt < 4; mt++)
      af[mt] = *(bf16x8*)&smA[(wm * 64 + mt * 16 + (lane & 15)) * 32 + (lane >> 4) * 8];
#pragma unroll
    for (int nt = 0; nt < 4; nt++)
      bfr[nt] = *(bf16x8*)&smB[(wn * 64 + nt * 16 + (lane & 15)) * 32 + (lane >> 4) * 8];
#pragma unroll
    for (int mt = 0; mt < 4; mt++)
#pragma unroll
      for (int nt = 0; nt < 4; nt++)
        acc[mt][nt] = __builtin_amdgcn_mfma_f32_16x16x32_bf16(af[mt], bfr[nt], acc[mt][nt], 0, 0, 0);
    __syncthreads();
  }
#pragma unroll
  for (int nt = 0; nt < 4; nt++) {
    int col = n0 + wn * 64 + nt * 16 + (lane & 15);
    if (col >= N) continue;
    float bval = BIAS ? bias[col] : 0.f;
#pragma unroll
    for (int mt = 0; mt < 4; mt++) {
      int rowb = m0 + wm * 64 + mt * 16 + (lane >> 4) * 4;
#pragma unroll
      for (int r = 0; r < 4; r++) {
        float v = acc[mt][nt][r] + bval;
        float* cp = Cb + (size_t)(rowb + r) * ldc + col;
        if (ACC) v += *cp;
        *cp = v;
      }
    }
  }
}

// ---- transpose+cast: W[K][N] fp32 -> Wt[Np][K] bf16 (zero pad rows >= N) ----
__global__ void tcast_kernel(const float* __restrict__ W, short* __restrict__ Wt,
                             int K, int N)
{
  __shared__ float tile[32][33];
  int n0 = blockIdx.x * 32, k0 = blockIdx.y * 32;
  int c = threadIdx.x & 31, r8 = threadIdx.x >> 5;
#pragma unroll
  for (int i = 0; i < 4; i++) {
    int r = r8 + i * 8;
    int n = n0 + c;
    tile[r][c] = (n < N) ? W[(size_t)(k0 + r) * N + n] : 0.f;
  }
  __syncthreads();
#pragma unroll
  for (int i = 0; i < 4; i++) {
    int r = r8 + i * 8;
    Wt[(size_t)(n0 + r) * K + k0 + c] = f2bf(tile[c][r]);
  }
}

// ---- gather+cast: Ag16[m][s*256+d] = x[b][s][t][d], m=b*2048+t ----
__global__ void gather_cast_kernel(const float* __restrict__ x, short* __restrict__ Ag)
{
  int idx = blockIdx.x * 256 + threadIdx.x;   // 8192*192
  int m = idx / 192;
  int g = idx - m * 192;
  int k = g * 4;
  int s = k >> 8, d = k & 255;
  int b = m >> 11, t = m & 2047;
  float4 v = *(const float4*)(x + ((size_t)((b * 3 + s) * 2048 + t) << 8) + d);
  *(short4*)(Ag + (size_t)m * 768 + k) = make_short4(f2bf(v.x), f2bf(v.y), f2bf(v.z), f2bf(v.w));
}

__global__ void cast_kernel(const float* __restrict__ in, short* __restrict__ out)
{
  size_t idx = (size_t)blockIdx.x * 256 + threadIdx.x;
  float4 v = *(const float4*)(in + idx * 4);
  *(short4*)(out + idx * 4) = make_short4(f2bf(v.x), f2bf(v.y), f2bf(v.z), f2bf(v.w));
}

// ---------------- LayerNorm over 512, in place + bf16 copy ----------------
__global__ void ln512_kernel(float* __restrict__ xio, const float* __restrict__ g,
                             const float* __restrict__ b, short* __restrict__ o16)
{
  const int row = blockIdx.x;
  const int lane = threadIdx.x;
  float* xr = xio + (size_t)row * 512;
  float4 v0 = *(float4*)(xr + lane * 4);
  float4 v1 = *(float4*)(xr + 256 + lane * 4);
  float sum = v0.x + v0.y + v0.z + v0.w + v1.x + v1.y + v1.z + v1.w;
#pragma unroll
  for (int o = 32; o >= 1; o >>= 1) sum += __shfl_xor(sum, o);
  const float mu = sum * (1.f / 512.f);
  float d[8] = {v0.x - mu, v0.y - mu, v0.z - mu, v0.w - mu,
                v1.x - mu, v1.y - mu, v1.z - mu, v1.w - mu};
  float vs = 0.f;
#pragma unroll
  for (int i = 0; i < 8; i++) vs += d[i] * d[i];
#pragma unroll
  for (int o = 32; o >= 1; o >>= 1) vs += __shfl_xor(vs, o);
  const float inv = rsqrtf(vs * (1.f / 512.f) + 1e-5f);
  float4 g0 = *(const float4*)(g + lane * 4);
  float4 g1 = *(const float4*)(g + 256 + lane * 4);
  float4 b0 = *(const float4*)(b + lane * 4);
  float4 b1 = *(const float4*)(b + 256 + lane * 4);
  v0.x = d[0] * inv * g0.x + b0.x; v0.y = d[1] * inv * g0.y + b0.y;
  v0.z = d[2] * inv * g0.z + b0.z; v0.w = d[3] * inv * g0.w + b0.w;
  v1.x = d[4] * inv * g1.x + b1.x; v1.y = d[5] * inv * g1.y + b1.y;
  v1.z = d[6] * inv * g1.z + b1.z; v1.w = d[7] * inv * g1.w + b1.w;
  *(float4*)(xr + lane * 4) = v0;
  *(float4*)(xr + 256 + lane * 4) = v1;
  short* orow = o16 + (size_t)row * 512;
  *(short4*)(orow + lane * 4) = make_short4(f2bf(v0.x), f2bf(v0.y), f2bf(v0.z), f2bf(v0.w));
  *(short4*)(orow + 256 + lane * 4) = make_short4(f2bf(v1.x), f2bf(v1.y), f2bf(v1.z), f2bf(v1.w));
}

// --------- dt = softplus(raw + dtb), logdA = -dt * exp(Alog) ---------
__global__ void dtprep_kernel(const float* __restrict__ Z, const float* __restrict__ dtb,
                              const float* __restrict__ Alog,
                              float* __restrict__ dtv, float* __restrict__ ldA)
{
  int idx = blockIdx.x * 256 + threadIdx.x;
  int row = idx >> 4, hh = idx & 15;
  float raw = Z[(size_t)row * 2320 + 2304 + hh] + dtb[hh];
  float dt = raw > 20.f ? raw : log1pf(expf(raw));
  dtv[idx] = dt;
  ldA[idx] = -dt * expf(Alog[hh]);
}

// ---- depthwise conv(4) + bias + silu ----
__global__ void conv_kernel(const float* __restrict__ Z, const float* __restrict__ convw,
                            const float* __restrict__ convb, float* __restrict__ xcv, int dir)
{
  int row = blockIdx.x;
  int c = blockIdx.y * 256 + threadIdx.x;
  int t = row & 2047;
  size_t bbase = (size_t)(row - t) * 2320;
  float wv[4] = {convw[c * 4 + 0], convw[c * 4 + 1], convw[c * 4 + 2], convw[c * 4 + 3]};
  float acc = convb[c];
#pragma unroll
  for (int k = 0; k < 4; k++) {
    int ts = dir ? (t + 3 - k) : (t - 3 + k);
    if (ts >= 0 && ts < 2048)
      acc += wv[k] * Z[bbase + (size_t)ts * 2320 + 1024 + c];
  }
  xcv[(size_t)row * 1280 + c] = acc * sigf(acc);
}

// ============ chunked SSD scan, Lc=64, 32 chunks ============
__global__ __launch_bounds__(256) void chunk_state_kernel(
    const float* __restrict__ xcv, const float* __restrict__ dtv,
    const float* __restrict__ ldA, float* __restrict__ Sbuf,
    float* __restrict__ Pbuf, int dir)
{
  const int bh = blockIdx.x, ck = blockIdx.y;
  const int b = bh >> 4, h = bh & 15;
  const int tid = threadIdx.x;
  __shared__ float sx[64][64];
  __shared__ float sB[64][128];
  __shared__ float sw[64];

  if (tid < 64) {
    int tg = ck * 64 + tid;
    int tt = dir ? 2047 - tg : tg;
    size_t r = (size_t)(b * 2048 + tt) * 16 + h;
    float v = ldA[r];
#pragma unroll
    for (int o = 1; o < 64; o <<= 1) { float u = __shfl_up(v, o); if (tid >= o) v += u; }
    float tot = __shfl(v, 63);
    sw[tid] = __expf(tot - v) * dtv[r];
    if (tid == 63) Pbuf[bh * 32 + ck] = __expf(tot);
  }
  for (int i4 = tid; i4 < 1024; i4 += 256) {
    int t = i4 >> 4, c4 = i4 & 15;
    int tg = ck * 64 + t; int tt = dir ? 2047 - tg : tg;
    *(float4*)&sx[t][c4 * 4] =
        *(const float4*)(xcv + (size_t)(b * 2048 + tt) * 1280 + h * 64 + c4 * 4);
  }
  for (int i4 = tid; i4 < 2048; i4 += 256) {
    int t = i4 >> 5, c4 = i4 & 31;
    int tg = ck * 64 + t; int tt = dir ? 2047 - tg : tg;
    *(float4*)&sB[t][c4 * 4] =
        *(const float4*)(xcv + (size_t)(b * 2048 + tt) * 1280 + 1024 + c4 * 4);
  }
  __syncthreads();
  const int p0 = (tid >> 4) * 4;
  const int n0 = (tid & 15) * 4;
  float acc[4][8];
#pragma unroll
  for (int i = 0; i < 4; i++)
#pragma unroll
    for (int j = 0; j < 8; j++) acc[i][j] = 0.f;
  for (int s = 0; s < 64; s++) {
    float w = sw[s];
    float4 xv = *(float4*)&sx[s][p0];
    float4 b0v = *(float4*)&sB[s][n0];
    float4 b1v = *(float4*)&sB[s][n0 + 64];
    float xw[4] = {xv.x * w, xv.y * w, xv.z * w, xv.w * w};
    float bb[8] = {b0v.x, b0v.y, b0v.z, b0v.w, b1v.x, b1v.y, b1v.z, b1v.w};
#pragma unroll
    for (int i = 0; i < 4; i++)
#pragma unroll
      for (int j = 0; j < 8; j++) acc[i][j] += xw[i] * bb[j];
  }
  float* Sp = Sbuf + ((size_t)(bh * 32 + ck) << 13);
#pragma unroll
  for (int i = 0; i < 4; i++) {
    *(float4*)(Sp + (p0 + i) * 128 + n0) = make_float4(acc[i][0], acc[i][1], acc[i][2], acc[i][3]);
    *(float4*)(Sp + (p0 + i) * 128 + n0 + 64) = make_float4(acc[i][4], acc[i][5], acc[i][6], acc[i][7]);
  }
}

__global__ void chunk_scan_kernel(float* __restrict__ Sbuf, const float* __restrict__ Pbuf)
{
  int idx = blockIdx.x * 256 + threadIdx.x;
  int bh = idx >> 13, elem = idx & 8191;
  float hh = 0.f;
  for (int ck = 0; ck < 32; ck++) {
    size_t off = ((size_t)(bh * 32 + ck) << 13) + elem;
    float s = Sbuf[off];
    float P = Pbuf[bh * 32 + ck];
    Sbuf[off] = hh;
    hh = P * hh + s;
  }
}

// chunk_out: y = M@x + exp(L_t) * (C @ Hpre^T) + Dh*x   (writes bf16)
__global__ __launch_bounds__(256) void chunk_out_kernel(
    const float* __restrict__ xcv, const float* __restrict__ dtv,
    const float* __restrict__ ldA, const float* __restrict__ Sbuf,
    const float* __restrict__ Dh, short* __restrict__ y, int dir)
{
  extern __shared__ float smem[];
  float (*sCt)[64] = (float(*)[64])smem;
  float (*sBt)[64] = (float(*)[64])(smem + 8192);
  float (*sx)[64]  = (float(*)[64])(smem + 16384);
  float (*sM)[64]  = (float(*)[64])(smem + 20480);
  float* sL  = smem + 24576;
  float* sdt = smem + 24640;

  const int bh = blockIdx.x, ck = blockIdx.y;
  const int b = bh >> 4, h = bh & 15;
  const int tid = threadIdx.x;

  if (tid < 64) {
    int tg = ck * 64 + tid;
    int tt = dir ? 2047 - tg : tg;
    size_t r = (size_t)(b * 2048 + tt) * 16 + h;
    float v = ldA[r];
#pragma unroll
    for (int o = 1; o < 64; o <<= 1) { float u = __shfl_up(v, o); if (tid >= o) v += u; }
    sL[tid] = v;
    sdt[tid] = dtv[r];
  }
  for (int i4 = tid; i4 < 2048; i4 += 256) {
    int t = i4 >> 5, c4 = i4 & 31;
    int tg = ck * 64 + t; int tt = dir ? 2047 - tg : tg;
    const float* rp = xcv + (size_t)(b * 2048 + tt) * 1280;
    float4 bv = *(const float4*)(rp + 1024 + c4 * 4);
    sBt[c4 * 4 + 0][t] = bv.x; sBt[c4 * 4 + 1][t] = bv.y;
    sBt[c4 * 4 + 2][t] = bv.z; sBt[c4 * 4 + 3][t] = bv.w;
    float4 cv = *(const float4*)(rp + 1152 + c4 * 4);
    sCt[c4 * 4 + 0][t] = cv.x; sCt[c4 * 4 + 1][t] = cv.y;
    sCt[c4 * 4 + 2][t] = cv.z; sCt[c4 * 4 + 3][t] = cv.w;
  }
  for (int i4 = tid; i4 < 1024; i4 += 256) {
    int t = i4 >> 4, c4 = i4 & 15;
    int tg = ck * 64 + t; int tt = dir ? 2047 - tg : tg;
    *(float4*)&sx[t][c4 * 4] =
        *(const float4*)(xcv + (size_t)(b * 2048 + tt) * 1280 + h * 64 + c4 * 4);
  }
  __syncthreads();

  const int i0 = (tid >> 4) * 4;
  const int j0 = (tid & 15) * 4;

  float acc[4][4];
#pragma unroll
  for (int i = 0; i < 4; i++)
#pragma unroll
    for (int j = 0; j < 4; j++) acc[i][j] = 0.f;
  for (int n = 0; n < 128; n++) {
    float4 cv = *(float4*)&sCt[n][i0];
    float4 bv = *(float4*)&sBt[n][j0];
    float cm[4] = {cv.x, cv.y, cv.z, cv.w};
    float bm[4] = {bv.x, bv.y, bv.z, bv.w};
#pragma unroll
    for (int i = 0; i < 4; i++)
#pragma unroll
      for (int j = 0; j < 4; j++) acc[i][j] += cm[i] * bm[j];
  }
#pragma unroll
  for (int ti = 0; ti < 4; ti++)
#pragma unroll
    for (int sj = 0; sj < 4; sj++) {
      int t = i0 + ti, s = j0 + sj;
      float v = (t >= s) ? acc[ti][sj] * __expf(sL[t] - sL[s]) * sdt[s] : 0.f;
      sM[s][t] = v;
    }
  __syncthreads();

  const float* Hp = Sbuf + ((size_t)(bh * 32 + ck) << 13);
  float4 hreg[8];
#pragma unroll
  for (int k = 0; k < 8; k++) {
    int i4 = tid + k * 256;
    hreg[k] = *(const float4*)(Hp + i4 * 4);
  }
  float yacc[4][4];
#pragma unroll
  for (int i = 0; i < 4; i++)
#pragma unroll
    for (int j = 0; j < 4; j++) yacc[i][j] = 0.f;
  for (int s = 0; s < 64; s++) {
    float4 mv = *(float4*)&sM[s][i0];
    float4 xv = *(float4*)&sx[s][j0];
    float mm[4] = {mv.x, mv.y, mv.z, mv.w};
    float xm[4] = {xv.x, xv.y, xv.z, xv.w};
#pragma unroll
    for (int i = 0; i < 4; i++)
#pragma unroll
      for (int j = 0; j < 4; j++) yacc[i][j] += mm[i] * xm[j];
  }
  __syncthreads();
#pragma unroll
  for (int k = 0; k < 8; k++) {
    int i4 = tid + k * 256;
    int p = i4 >> 5, c4 = i4 & 31;
    sBt[c4 * 4 + 0][p] = hreg[k].x; sBt[c4 * 4 + 1][p] = hreg[k].y;
    sBt[c4 * 4 + 2][p] = hreg[k].z; sBt[c4 * 4 + 3][p] = hreg[k].w;
  }
  __syncthreads();

  float acc2[4][4];
#pragma unroll
  for (int i = 0; i < 4; i++)
#pragma unroll
    for (int j = 0; j < 4; j++) acc2[i][j] = 0.f;
  for (int n = 0; n < 128; n++) {
    float4 cv = *(float4*)&sCt[n][i0];
    float4 hv = *(float4*)&sBt[n][j0];
    float cm[4] = {cv.x, cv.y, cv.z, cv.w};
    float hm[4] = {hv.x, hv.y, hv.z, hv.w};
#pragma unroll
    for (int i = 0; i < 4; i++)
#pragma unroll
      for (int j = 0; j < 4; j++) acc2[i][j] += cm[i] * hm[j];
  }
  const float dh = Dh[h];
#pragma unroll
  for (int ti = 0; ti < 4; ti++) {
    int t = i0 + ti;
    float e = __expf(sL[t]);
    int tg = ck * 64 + t; int tt = dir ? 2047 - tg : tg;
    float o0 = yacc[ti][0] + e * acc2[ti][0] + dh * sx[t][j0 + 0];
    float o1 = yacc[ti][1] + e * acc2[ti][1] + dh * sx[t][j0 + 1];
    float o2 = yacc[ti][2] + e * acc2[ti][2] + dh * sx[t][j0 + 2];
    float o3 = yacc[ti][3] + e * acc2[ti][3] + dh * sx[t][j0 + 3];
    *(short4*)(y + (size_t)(b * 2048 + tt) * 1024 + h * 64 + j0) =
        make_short4(f2bf(o0), f2bf(o1), f2bf(o2), f2bf(o3));
  }
}

// ------ y16 = bf16(rmsnorm(y16 * silu(z)) * normw), in place ------
__global__ void rms_kernel(short* __restrict__ y, const float* __restrict__ Z,
                           const float* __restrict__ normw)
{
  const int row = blockIdx.x;
  const int lane = threadIdx.x;
  short* yr = y + (size_t)row * 1024;
  const float* zr = Z + (size_t)row * 2320;
  float vals[16];
  float ss = 0.f;
#pragma unroll
  for (int jj = 0; jj < 4; jj++) {
    int off = jj * 256 + lane * 4;
    short4 yv = *(short4*)(yr + off);
    float4 zv = *(const float4*)(zr + off);
    float a0 = bf2f(yv.x) * (zv.x * sigf(zv.x));
    float a1 = bf2f(yv.y) * (zv.y * sigf(zv.y));
    float a2 = bf2f(yv.z) * (zv.z * sigf(zv.z));
    float a3 = bf2f(yv.w) * (zv.w * sigf(zv.w));
    vals[jj * 4 + 0] = a0; vals[jj * 4 + 1] = a1;
    vals[jj * 4 + 2] = a2; vals[jj * 4 + 3] = a3;
    ss += a0 * a0 + a1 * a1 + a2 * a2 + a3 * a3;
  }
#pragma unroll
  for (int o = 32; o >= 1; o >>= 1) ss += __shfl_xor(ss, o);
  const float scale = rsqrtf(ss * (1.f / 1024.f) + 1e-5f);
#pragma unroll
  for (int jj = 0; jj < 4; jj++) {
    int off = jj * 256 + lane * 4;
    float4 nw = *(const float4*)(normw + off);
    *(short4*)(yr + off) = make_short4(
        f2bf(vals[jj * 4 + 0] * scale * nw.x), f2bf(vals[jj * 4 + 1] * scale * nw.y),
        f2bf(vals[jj * 4 + 2] * scale * nw.z), f2bf(vals[jj * 4 + 3] * scale * nw.w));
  }
}

// ---- ob16 = bf16(od * silu(h)) over 8192x512 ----
__global__ void combine_kernel(const float* __restrict__ od, const float* __restrict__ h,
                               short* __restrict__ ob)
{
  size_t idx = (size_t)blockIdx.x * 256 + threadIdx.x;
  float4 o = ((const float4*)od)[idx];
  float4 g = ((const float4*)h)[idx];
  o.x *= g.x * sigf(g.x);
  o.y *= g.y * sigf(g.y);
  o.z *= g.z * sigf(g.z);
  o.w *= g.w * sigf(g.w);
  *(short4*)(ob + idx * 4) = make_short4(f2bf(o.x), f2bf(o.y), f2bf(o.z), f2bf(o.w));
}

__global__ void lnshort_kernel(const float* __restrict__ v, const float* __restrict__ g,
                               const float* __restrict__ b, const float* __restrict__ shortcut,
                               float* __restrict__ out0, short* __restrict__ fn)
{
  const int row = blockIdx.x;
  const int lane = threadIdx.x;
  size_t base = (size_t)row * 256;
  float4 x = *(const float4*)(v + base + lane * 4);
  float sum = x.x + x.y + x.z + x.w;
#pragma unroll
  for (int o = 32; o >= 1; o >>= 1) sum += __shfl_xor(sum, o);
  const float mu = sum * (1.f / 256.f);
  float d[4] = {x.x - mu, x.y - mu, x.z - mu, x.w - mu};
  float vs = d[0] * d[0] + d[1] * d[1] + d[2] * d[2] + d[3] * d[3];
#pragma unroll
  for (int o = 32; o >= 1; o >>= 1) vs += __shfl_xor(vs, o);
  const float inv = rsqrtf(vs * (1.f / 256.f) + 1e-5f);
  float4 gg = *(const float4*)(g + lane * 4);
  float4 bb = *(const float4*)(b + lane * 4);
  float4 sc = *(const float4*)(shortcut + base + lane * 4);
  float4 o4;
  o4.x = d[0] * inv * gg.x + bb.x + sc.x;
  o4.y = d[1] * inv * gg.y + bb.y + sc.y;
  o4.z = d[2] * inv * gg.z + bb.z + sc.z;
  o4.w = d[3] * inv * gg.w + bb.w + sc.w;
  *(float4*)(out0 + base + lane * 4) = o4;
  float ns = o4.x * o4.x + o4.y * o4.y + o4.z * o4.z + o4.w * o4.w;
#pragma unroll
  for (int o = 32; o >= 1; o >>= 1) ns += __shfl_xor(ns, o);
  const float r = 1.f / fmaxf(sqrtf(ns), 1e-12f);
  *(short4*)(fn + base + lane * 4) =
      make_short4(f2bf(o4.x * r), f2bf(o4.y * r), f2bf(o4.z * r), f2bf(o4.w * r));
}

extern "C" void kernel_launch(void* const* d_in, const int* in_sizes, int n_in,
                              void* d_out, int out_size, void* d_ws, size_t ws_size,
                              hipStream_t stream)
{
  (void)in_sizes; (void)n_in; (void)out_size; (void)ws_size;
  const float* x        = (const float*)d_in[0];
  const float* Wp       = (const float*)d_in[1];
  const float* bp       = (const float*)d_in[2];
  const float* Wpre     = (const float*)d_in[3];
  const float* bpre     = (const float*)d_in[4];
  const float* lnpre_g  = (const float*)d_in[5];
  const float* lnpre_b  = (const float*)d_in[6];
  const float* Wpost    = (const float*)d_in[7];
  const float* bpost    = (const float*)d_in[8];
  const float* lnpost_g = (const float*)d_in[9];
  const float* lnpost_b = (const float*)d_in[10];

  // ws layout (float units), total ~189.7 MiB
  float* ws   = (float*)d_ws;
  float* Zb   = ws;                        // 19,005,440
  float* xcv  = Zb + 19005440;             // 10,485,760 (+overlays below)
  float* xc   = xcv + 10485760;            // 2,097,152
  float* hbuf = xc + 2097152;              // 4,194,304
  short* hb16 = (short*)(hbuf + 4194304);  // 4,194,304 sh (2,097,152 fl)
  float* yb16f= hbuf + 4194304 + 2097152;  // yb16 region: 4,194,304 fl
  short* yb16 = (short*)yb16f;             // 8,388,608 sh
  float* od   = yb16f + 4194304;           // 4,194,304
  float* dtv  = od + 4194304;              // 131,072
  float* ldA  = dtv + 131072;              // 131,072
  float* Pbuf = ldA + 131072;              // 2,048
  short* WinT = (short*)(Pbuf + 2048);     // 1,245,184 sh (2432x512)
  short* WoutT= WinT + 1245184;            // 524,288 sh (512x1024)

  // overlays in xcv region (10,485,760 fl):
  short* Ag16   = (short*)xcv;                 // 8192x768 sh = 3,145,728 fl (until gather gemm)
  short* WpT    = (short*)(xcv + 3145728);     // 256x768 sh
  short* xcb    = (short*)xcv;                 // 8192x256 sh = 1,048,576 fl (until pre gemm)
  short* WpreT  = (short*)(xcv + 1048576);     // 512x256 sh (abuts xcb, no overlap)
  short* ob16   = (short*)xcv;                 // 8192x512 sh = 2,097,152 fl (after xcv dead)
  short* WpostT = (short*)(xcv + 2097152);     // 256x512 sh — MOVED past ob16 (was overlapping!)
  // overlays in yb16 region (dead after out_proj dir1):
  float* vbuf = yb16f;                         // 2,097,152 fl
  short* fn16 = (short*)(yb16f + 2097152);     // 2,097,152 sh

  float* out0 = (float*)d_out;
  float* attn = out0 + 2097152;
  float* Sbuf = attn;                          // 64*32*8192 fl == attn region

  // --- gather proj ---
  tcast_kernel<<<dim3(8, 24), 256, 0, stream>>>(Wp, WpT, 768, 256);
  gather_cast_kernel<<<6144, 256, 0, stream>>>(x, Ag16);
  gemm16_kernel<true, false><<<dim3(64, 2), 256, 0, stream>>>(Ag16, WpT, bp, xc, 8192, 256, 768, 256, 0, 0, 0);
  // --- pre proj + LN ---
  cast_kernel<<<2048, 256, 0, stream>>>(xc, xcb);
  tcast_kernel<<<dim3(16, 8), 256, 0, stream>>>(Wpre, WpreT, 256, 512);
  gemm16_kernel<true, false><<<dim3(64, 4), 256, 0, stream>>>(xcb, WpreT, bpre, hbuf, 8192, 512, 256, 512, 0, 0, 0);
  ln512_kernel<<<8192, 64, 0, stream>>>(hbuf, lnpre_g, lnpre_b, hb16);

  for (int dir = 0; dir < 2; dir++) {
    const float* Win   = (const float*)d_in[11 + dir * 8];
    const float* convw = (const float*)d_in[12 + dir * 8];
    const float* convb = (const float*)d_in[13 + dir * 8];
    const float* dtb   = (const float*)d_in[14 + dir * 8];
    const float* Alog  = (const float*)d_in[15 + dir * 8];
    const float* Dh    = (const float*)d_in[16 + dir * 8];
    const float* normw = (const float*)d_in[17 + dir * 8];
    const float* Wout  = (const float*)d_in[18 + dir * 8];

    tcast_kernel<<<dim3(76, 16), 256, 0, stream>>>(Win, WinT, 512, 2320);
    tcast_kernel<<<dim3(16, 32), 256, 0, stream>>>(Wout, WoutT, 1024, 512);
    gemm16_kernel<false, false><<<dim3(64, 19), 256, 0, stream>>>(hb16, WinT, nullptr, Zb, 8192, 2320, 512, 2320, 0, 0, 0);
    dtprep_kernel<<<512, 256, 0, stream>>>(Zb, dtb, Alog, dtv, ldA);
    conv_kernel<<<dim3(8192, 5), 256, 0, stream>>>(Zb, convw, convb, xcv, dir);
    chunk_state_kernel<<<dim3(64, 32), 256, 0, stream>>>(xcv, dtv, ldA, Sbuf, Pbuf, dir);
    chunk_scan_kernel<<<2048, 256, 0, stream>>>(Sbuf, Pbuf);
    chunk_out_kernel<<<dim3(64, 32), 256, 98816, stream>>>(xcv, dtv, ldA, Sbuf, Dh, yb16, dir);
    rms_kernel<<<8192, 64, 0, stream>>>(yb16, Zb, normw);
    if (dir == 0)
      gemm16_kernel<false, false><<<dim3(64, 4), 256, 0, stream>>>(yb16, WoutT, nullptr, od, 8192, 512, 1024, 512, 0, 0, 0);
    else
      gemm16_kernel<false, true><<<dim3(64, 4), 256, 0, stream>>>(yb16, WoutT, nullptr, od, 8192, 512, 1024, 512, 0, 0, 0);
  }

  combine_kernel<<<4096, 256, 0, stream>>>(od, hbuf, ob16);
  tcast_kernel<<<dim3(8, 16), 256, 0, stream>>>(Wpost, WpostT, 512, 256);
  gemm16_kernel<true, false><<<dim3(64, 2), 256, 0, stream>>>(ob16, WpostT, bpost, vbuf, 8192, 256, 512, 256, 0, 0, 0);
  lnshort_kernel<<<8192, 64, 0, stream>>>(vbuf, lnpost_g, lnpost_b, xc, out0, fn16);
  gemm16_kernel<false, false><<<dim3(16, 16, 4), 256, 0, stream>>>(
      fn16, fn16, nullptr, attn, 2048, 2048, 256, 2048,
      (long long)2048 * 256, (long long)2048 * 256, (long long)2048 * 2048);
}

// Round 5
// 730.736 us; speedup vs baseline: 4.9711x; 1.4169x over previous
//
#include <hip/hip_runtime.h>
#include <math.h>

__device__ __forceinline__ float sigf(float v) { return 1.f / (1.f + __expf(-v)); }

__device__ __forceinline__ short f2bf(float f) {
  unsigned int u = __builtin_bit_cast(unsigned int, f);
  unsigned int r = (u + 0x7fffu + ((u >> 16) & 1u)) >> 16;
  return (short)r;
}
__device__ __forceinline__ float bf2f(short s) {
  unsigned int u = ((unsigned int)(unsigned short)s) << 16;
  return __builtin_bit_cast(float, u);
}

typedef short bf16x8 __attribute__((ext_vector_type(8)));
typedef float f32x4 __attribute__((ext_vector_type(4)));

__device__ __forceinline__ void async16(const short* g, short* l) {
  __builtin_amdgcn_global_load_lds(
      (const __attribute__((address_space(1))) unsigned int*)g,
      (__attribute__((address_space(3))) unsigned int*)l, 16, 0, 0);
}

// ============ bf16 MFMA GEMM: C[M,N] += A[M,K] @ Bt[N,K]^T ============
template<bool BIAS, bool ACC>
__global__ __launch_bounds__(256) void gemm16_kernel(
    const short* __restrict__ A, const short* __restrict__ Bt,
    const float* __restrict__ bias, float* __restrict__ C,
    int M, int N, int K, int ldc,
    long long sAb, long long sBb, long long sCb)
{
  __shared__ short smA[128 * 32];
  __shared__ short smB[128 * 32];
  const int tid = threadIdx.x;
  const int wave = tid >> 6;
  const int lane = tid & 63;
  const int m0 = blockIdx.x * 128;
  const int n0 = blockIdx.y * 128;
  const int bz = blockIdx.z;
  const short* Ab = A + (size_t)bz * sAb;
  const short* Bb = Bt + (size_t)bz * sBb;
  float* Cb = C + (size_t)bz * sCb;

  f32x4 acc[4][4] = {};

  const int isB = wave >> 1;
  const int half = wave & 1;
  const short* gsrc = isB ? Bb : Ab;
  short* ldsbase = isB ? smB : smA;
  const int tile_r0 = isB ? n0 : m0;
  const int lrow = lane >> 2;
  const int lk = (lane & 3) * 8;

  const int wm = wave >> 1, wn = wave & 1;

  for (int k0 = 0; k0 < K; k0 += 32) {
#pragma unroll
    for (int c = 0; c < 4; c++) {
      int row = half * 64 + c * 16 + lrow;
      const short* g = gsrc + (size_t)(tile_r0 + row) * K + k0 + lk;
      short* l = ldsbase + (half * 64 + c * 16) * 32;
      async16(g, l);
    }
    __syncthreads();
    bf16x8 af[4], bfr[4];
#pragma unroll
    for (int mt = 0; mt < 4; mt++)
      af[mt] = *(bf16x8*)&smA[(wm * 64 + mt * 16 + (lane & 15)) * 32 + (lane >> 4) * 8];
#pragma unroll
    for (int nt = 0; nt < 4; nt++)
      bfr[nt] = *(bf16x8*)&smB[(wn * 64 + nt * 16 + (lane & 15)) * 32 + (lane >> 4) * 8];
#pragma unroll
    for (int mt = 0; mt < 4; mt++)
#pragma unroll
      for (int nt = 0; nt < 4; nt++)
        acc[mt][nt] = __builtin_amdgcn_mfma_f32_16x16x32_bf16(af[mt], bfr[nt], acc[mt][nt], 0, 0, 0);
    __syncthreads();
  }
#pragma unroll
  for (int nt = 0; nt < 4; nt++) {
    int col = n0 + wn * 64 + nt * 16 + (lane & 15);
    if (col >= N) continue;
    float bval = BIAS ? bias[col] : 0.f;
#pragma unroll
    for (int mt = 0; mt < 4; mt++) {
      int rowb = m0 + wm * 64 + mt * 16 + (lane >> 4) * 4;
#pragma unroll
      for (int r = 0; r < 4; r++) {
        float v = acc[mt][nt][r] + bval;
        float* cp = Cb + (size_t)(rowb + r) * ldc + col;
        if (ACC) v += *cp;
        *cp = v;
      }
    }
  }
}

// ---- transpose+cast: W[K][N] fp32 -> Wt[Np][K] bf16 (zero pad rows >= N) ----
__global__ void tcast_kernel(const float* __restrict__ W, short* __restrict__ Wt,
                             int K, int N)
{
  __shared__ float tile[32][33];
  int n0 = blockIdx.x * 32, k0 = blockIdx.y * 32;
  int c = threadIdx.x & 31, r8 = threadIdx.x >> 5;
#pragma unroll
  for (int i = 0; i < 4; i++) {
    int r = r8 + i * 8;
    int n = n0 + c;
    tile[r][c] = (n < N) ? W[(size_t)(k0 + r) * N + n] : 0.f;
  }
  __syncthreads();
#pragma unroll
  for (int i = 0; i < 4; i++) {
    int r = r8 + i * 8;
    Wt[(size_t)(n0 + r) * K + k0 + c] = f2bf(tile[c][r]);
  }
}

// ---- gather+cast: Ag16[m][s*256+d] = x[b][s][t][d], m=b*2048+t ----
__global__ void gather_cast_kernel(const float* __restrict__ x, short* __restrict__ Ag)
{
  int idx = blockIdx.x * 256 + threadIdx.x;
  int m = idx / 192;
  int g = idx - m * 192;
  int k = g * 4;
  int s = k >> 8, d = k & 255;
  int b = m >> 11, t = m & 2047;
  float4 v = *(const float4*)(x + ((size_t)((b * 3 + s) * 2048 + t) << 8) + d);
  *(short4*)(Ag + (size_t)m * 768 + k) = make_short4(f2bf(v.x), f2bf(v.y), f2bf(v.z), f2bf(v.w));
}

__global__ void cast_kernel(const float* __restrict__ in, short* __restrict__ out)
{
  size_t idx = (size_t)blockIdx.x * 256 + threadIdx.x;
  float4 v = *(const float4*)(in + idx * 4);
  *(short4*)(out + idx * 4) = make_short4(f2bf(v.x), f2bf(v.y), f2bf(v.z), f2bf(v.w));
}

// ---------------- LayerNorm over 512, in place + bf16 copy ----------------
__global__ void ln512_kernel(float* __restrict__ xio, const float* __restrict__ g,
                             const float* __restrict__ b, short* __restrict__ o16)
{
  const int row = blockIdx.x;
  const int lane = threadIdx.x;
  float* xr = xio + (size_t)row * 512;
  float4 v0 = *(float4*)(xr + lane * 4);
  float4 v1 = *(float4*)(xr + 256 + lane * 4);
  float sum = v0.x + v0.y + v0.z + v0.w + v1.x + v1.y + v1.z + v1.w;
#pragma unroll
  for (int o = 32; o >= 1; o >>= 1) sum += __shfl_xor(sum, o);
  const float mu = sum * (1.f / 512.f);
  float d[8] = {v0.x - mu, v0.y - mu, v0.z - mu, v0.w - mu,
                v1.x - mu, v1.y - mu, v1.z - mu, v1.w - mu};
  float vs = 0.f;
#pragma unroll
  for (int i = 0; i < 8; i++) vs += d[i] * d[i];
#pragma unroll
  for (int o = 32; o >= 1; o >>= 1) vs += __shfl_xor(vs, o);
  const float inv = rsqrtf(vs * (1.f / 512.f) + 1e-5f);
  float4 g0 = *(const float4*)(g + lane * 4);
  float4 g1 = *(const float4*)(g + 256 + lane * 4);
  float4 b0 = *(const float4*)(b + lane * 4);
  float4 b1 = *(const float4*)(b + 256 + lane * 4);
  v0.x = d[0] * inv * g0.x + b0.x; v0.y = d[1] * inv * g0.y + b0.y;
  v0.z = d[2] * inv * g0.z + b0.z; v0.w = d[3] * inv * g0.w + b0.w;
  v1.x = d[4] * inv * g1.x + b1.x; v1.y = d[5] * inv * g1.y + b1.y;
  v1.z = d[6] * inv * g1.z + b1.z; v1.w = d[7] * inv * g1.w + b1.w;
  *(float4*)(xr + lane * 4) = v0;
  *(float4*)(xr + 256 + lane * 4) = v1;
  short* orow = o16 + (size_t)row * 512;
  *(short4*)(orow + lane * 4) = make_short4(f2bf(v0.x), f2bf(v0.y), f2bf(v0.z), f2bf(v0.w));
  *(short4*)(orow + 256 + lane * 4) = make_short4(f2bf(v1.x), f2bf(v1.y), f2bf(v1.z), f2bf(v1.w));
}

// --------- dt = softplus(raw + dtb), logdA = -dt * exp(Alog) ---------
__global__ void dtprep_kernel(const float* __restrict__ Z, const float* __restrict__ dtb,
                              const float* __restrict__ Alog,
                              float* __restrict__ dtv, float* __restrict__ ldA)
{
  int idx = blockIdx.x * 256 + threadIdx.x;
  int row = idx >> 4, hh = idx & 15;
  float raw = Z[(size_t)row * 2320 + 2304 + hh] + dtb[hh];
  float dt = raw > 20.f ? raw : log1pf(expf(raw));
  dtv[idx] = dt;
  ldA[idx] = -dt * expf(Alog[hh]);
}

// ---- depthwise conv(4) + bias + silu ----
__global__ void conv_kernel(const float* __restrict__ Z, const float* __restrict__ convw,
                            const float* __restrict__ convb, float* __restrict__ xcv, int dir)
{
  int row = blockIdx.x;
  int c = blockIdx.y * 256 + threadIdx.x;
  int t = row & 2047;
  size_t bbase = (size_t)(row - t) * 2320;
  float wv[4] = {convw[c * 4 + 0], convw[c * 4 + 1], convw[c * 4 + 2], convw[c * 4 + 3]};
  float acc = convb[c];
#pragma unroll
  for (int k = 0; k < 4; k++) {
    int ts = dir ? (t + 3 - k) : (t - 3 + k);
    if (ts >= 0 && ts < 2048)
      acc += wv[k] * Z[bbase + (size_t)ts * 2320 + 1024 + c];
  }
  xcv[(size_t)row * 1280 + c] = acc * sigf(acc);
}

// ============ chunked SSD scan, Lc=64, 32 chunks ============
__global__ __launch_bounds__(256) void chunk_state_kernel(
    const float* __restrict__ xcv, const float* __restrict__ dtv,
    const float* __restrict__ ldA, float* __restrict__ Sbuf,
    float* __restrict__ Pbuf, int dir)
{
  const int bh = blockIdx.x, ck = blockIdx.y;
  const int b = bh >> 4, h = bh & 15;
  const int tid = threadIdx.x;
  __shared__ float sx[64][64];
  __shared__ float sB[64][128];
  __shared__ float sw[64];

  if (tid < 64) {
    int tg = ck * 64 + tid;
    int tt = dir ? 2047 - tg : tg;
    size_t r = (size_t)(b * 2048 + tt) * 16 + h;
    float v = ldA[r];
#pragma unroll
    for (int o = 1; o < 64; o <<= 1) { float u = __shfl_up(v, o); if (tid >= o) v += u; }
    float tot = __shfl(v, 63);
    sw[tid] = __expf(tot - v) * dtv[r];
    if (tid == 63) Pbuf[bh * 32 + ck] = __expf(tot);
  }
  for (int i4 = tid; i4 < 1024; i4 += 256) {
    int t = i4 >> 4, c4 = i4 & 15;
    int tg = ck * 64 + t; int tt = dir ? 2047 - tg : tg;
    *(float4*)&sx[t][c4 * 4] =
        *(const float4*)(xcv + (size_t)(b * 2048 + tt) * 1280 + h * 64 + c4 * 4);
  }
  for (int i4 = tid; i4 < 2048; i4 += 256) {
    int t = i4 >> 5, c4 = i4 & 31;
    int tg = ck * 64 + t; int tt = dir ? 2047 - tg : tg;
    *(float4*)&sB[t][c4 * 4] =
        *(const float4*)(xcv + (size_t)(b * 2048 + tt) * 1280 + 1024 + c4 * 4);
  }
  __syncthreads();
  const int p0 = (tid >> 4) * 4;
  const int n0 = (tid & 15) * 4;
  float acc[4][8];
#pragma unroll
  for (int i = 0; i < 4; i++)
#pragma unroll
    for (int j = 0; j < 8; j++) acc[i][j] = 0.f;
  for (int s = 0; s < 64; s++) {
    float w = sw[s];
    float4 xv = *(float4*)&sx[s][p0];
    float4 b0v = *(float4*)&sB[s][n0];
    float4 b1v = *(float4*)&sB[s][n0 + 64];
    float xw[4] = {xv.x * w, xv.y * w, xv.z * w, xv.w * w};
    float bb[8] = {b0v.x, b0v.y, b0v.z, b0v.w, b1v.x, b1v.y, b1v.z, b1v.w};
#pragma unroll
    for (int i = 0; i < 4; i++)
#pragma unroll
      for (int j = 0; j < 8; j++) acc[i][j] += xw[i] * bb[j];
  }
  float* Sp = Sbuf + ((size_t)(bh * 32 + ck) << 13);
#pragma unroll
  for (int i = 0; i < 4; i++) {
    *(float4*)(Sp + (p0 + i) * 128 + n0) = make_float4(acc[i][0], acc[i][1], acc[i][2], acc[i][3]);
    *(float4*)(Sp + (p0 + i) * 128 + n0 + 64) = make_float4(acc[i][4], acc[i][5], acc[i][6], acc[i][7]);
  }
}

__global__ void chunk_scan_kernel(float* __restrict__ Sbuf, const float* __restrict__ Pbuf)
{
  int idx = blockIdx.x * 256 + threadIdx.x;
  int bh = idx >> 13, elem = idx & 8191;
  float hh = 0.f;
  for (int ck = 0; ck < 32; ck++) {
    size_t off = ((size_t)(bh * 32 + ck) << 13) + elem;
    float s = Sbuf[off];
    float P = Pbuf[bh * 32 + ck];
    Sbuf[off] = hh;
    hh = P * hh + s;
  }
}

// ======== chunk_out (MFMA): y = P@X + exp(L_t)*(C@H^T) + Dh*x, bf16 out ========
// Per block: scores S=C@B^T (64x64x128), mask/decay -> P (bf16, LDS),
// intra y1=P@X (64x64x64), inter y2=C@H^T (64x64x128). 4 waves x 16 rows.
__global__ __launch_bounds__(256) void chunk_out_kernel(
    const float* __restrict__ xcv, const float* __restrict__ dtv,
    const float* __restrict__ ldA, const float* __restrict__ Sbuf,
    const float* __restrict__ Dh, short* __restrict__ y, int dir)
{
  extern __shared__ short smem16[];
  short* sC  = smem16;            // [64][136] bf16, C[t][n]
  short* sB  = sC + 64 * 136;     // [64][136] bf16, B[s][n]
  short* sH  = sB + 64 * 136;     // [64][136] bf16, H[p][n]
  short* sXT = sH + 64 * 136;     // [64][72]  bf16, X^T[p][s]
  short* sP  = sXT + 64 * 72;     // [64][72]  bf16, P[t][s]; later y[t][p]
  float* sL  = (float*)(sP + 64 * 72);  // [64]
  float* sdt = sL + 64;                 // [64]

  const int bh = blockIdx.x, ck = blockIdx.y;
  const int b = bh >> 4, h = bh & 15;
  const int tid = threadIdx.x;
  const int wave = tid >> 6, lane = tid & 63;

  if (tid < 64) {
    int tg = ck * 64 + tid;
    int tt = dir ? 2047 - tg : tg;
    size_t r = (size_t)(b * 2048 + tt) * 16 + h;
    float v = ldA[r];
#pragma unroll
    for (int o = 1; o < 64; o <<= 1) { float u = __shfl_up(v, o); if (tid >= o) v += u; }
    sL[tid] = v;
    sdt[tid] = dtv[r];
  }
  // stage C, B (bf16, n-contiguous)
  for (int i4 = tid; i4 < 2048; i4 += 256) {
    int t = i4 >> 5, c4 = i4 & 31;
    int tg = ck * 64 + t; int tt = dir ? 2047 - tg : tg;
    const float* rp = xcv + (size_t)(b * 2048 + tt) * 1280;
    float4 bv = *(const float4*)(rp + 1024 + c4 * 4);
    *(short4*)&sB[t * 136 + c4 * 4] = make_short4(f2bf(bv.x), f2bf(bv.y), f2bf(bv.z), f2bf(bv.w));
    float4 cv = *(const float4*)(rp + 1152 + c4 * 4);
    *(short4*)&sC[t * 136 + c4 * 4] = make_short4(f2bf(cv.x), f2bf(cv.y), f2bf(cv.z), f2bf(cv.w));
  }
  // stage X^T (bf16 transposed)
  for (int i4 = tid; i4 < 1024; i4 += 256) {
    int t = i4 >> 4, p0 = (i4 & 15) * 4;
    int tg = ck * 64 + t; int tt = dir ? 2047 - tg : tg;
    float4 xv = *(const float4*)(xcv + (size_t)(b * 2048 + tt) * 1280 + h * 64 + p0);
    sXT[(p0 + 0) * 72 + t] = f2bf(xv.x);
    sXT[(p0 + 1) * 72 + t] = f2bf(xv.y);
    sXT[(p0 + 2) * 72 + t] = f2bf(xv.z);
    sXT[(p0 + 3) * 72 + t] = f2bf(xv.w);
  }
  // stage H (entering chunk state, [p][n])
  const float* Hp = Sbuf + ((size_t)(bh * 32 + ck) << 13);
  for (int i4 = tid; i4 < 2048; i4 += 256) {
    int p = i4 >> 5, c4 = i4 & 31;
    float4 hv = *(const float4*)(Hp + p * 128 + c4 * 4);
    *(short4*)&sH[p * 136 + c4 * 4] = make_short4(f2bf(hv.x), f2bf(hv.y), f2bf(hv.z), f2bf(hv.w));
  }
  __syncthreads();

  const int mcol = lane & 15;          // A-frag m / B-frag n
  const int kgrp = (lane >> 4) * 8;    // k offset within 32-chunk
  const int mrow = wave * 16 + mcol;

  // A-frags of C (shared by scores and inter)
  bf16x8 afC[4];
#pragma unroll
  for (int kk = 0; kk < 4; kk++)
    afC[kk] = *(bf16x8*)&sC[mrow * 136 + kk * 32 + kgrp];

  // scores
  f32x4 sacc[4] = {};
#pragma unroll
  for (int j = 0; j < 4; j++)
#pragma unroll
    for (int kk = 0; kk < 4; kk++) {
      bf16x8 bf = *(bf16x8*)&sB[(j * 16 + mcol) * 136 + kk * 32 + kgrp];
      sacc[j] = __builtin_amdgcn_mfma_f32_16x16x32_bf16(afC[kk], bf, sacc[j], 0, 0, 0);
    }

  // decay + mask -> P (bf16)
  const int rbase = wave * 16 + (lane >> 4) * 4;
  float Lt[4];
#pragma unroll
  for (int r = 0; r < 4; r++) Lt[r] = sL[rbase + r];
#pragma unroll
  for (int j = 0; j < 4; j++) {
    int s = j * 16 + mcol;
    float Ls = sL[s], ds = sdt[s];
#pragma unroll
    for (int r = 0; r < 4; r++) {
      int t = rbase + r;
      float v = (t >= s) ? sacc[j][r] * __expf(Lt[r] - Ls) * ds : 0.f;
      sP[t * 72 + s] = f2bf(v);
    }
  }
  __syncthreads();

  // intra: y1 = P @ X (K=64)
  bf16x8 afP[2];
#pragma unroll
  for (int kk = 0; kk < 2; kk++)
    afP[kk] = *(bf16x8*)&sP[mrow * 72 + kk * 32 + kgrp];
  f32x4 yacc[4] = {};
#pragma unroll
  for (int j = 0; j < 4; j++)
#pragma unroll
    for (int kk = 0; kk < 2; kk++) {
      bf16x8 bf = *(bf16x8*)&sXT[(j * 16 + mcol) * 72 + kk * 32 + kgrp];
      yacc[j] = __builtin_amdgcn_mfma_f32_16x16x32_bf16(afP[kk], bf, yacc[j], 0, 0, 0);
    }
  // inter: y2 = C @ H^T (K=128)
  f32x4 y2[4] = {};
#pragma unroll
  for (int j = 0; j < 4; j++)
#pragma unroll
    for (int kk = 0; kk < 4; kk++) {
      bf16x8 bf = *(bf16x8*)&sH[(j * 16 + mcol) * 136 + kk * 32 + kgrp];
      y2[j] = __builtin_amdgcn_mfma_f32_16x16x32_bf16(afC[kk], bf, y2[j], 0, 0, 0);
    }

  // combine: y = y1 + exp(Lt)*y2 + Dh*x
  const float dh = Dh[h];
  float eL[4];
#pragma unroll
  for (int r = 0; r < 4; r++) eL[r] = __expf(Lt[r]);
#pragma unroll
  for (int j = 0; j < 4; j++) {
    int p = j * 16 + mcol;
#pragma unroll
    for (int r = 0; r < 4; r++) {
      float xv = bf2f(sXT[p * 72 + rbase + r]);
      yacc[j][r] = yacc[j][r] + eL[r] * y2[j][r] + dh * xv;
    }
  }
  __syncthreads();   // all P reads done; reuse sP as y[t][p]
#pragma unroll
  for (int j = 0; j < 4; j++) {
    int p = j * 16 + mcol;
#pragma unroll
    for (int r = 0; r < 4; r++)
      sP[(rbase + r) * 72 + p] = f2bf(yacc[j][r]);
  }
  __syncthreads();
  // coalesced bf16 store
  for (int i4 = tid; i4 < 1024; i4 += 256) {
    int t = i4 >> 4, p0 = (i4 & 15) * 4;
    int tg = ck * 64 + t; int tt = dir ? 2047 - tg : tg;
    *(short4*)(y + (size_t)(b * 2048 + tt) * 1024 + h * 64 + p0) = *(short4*)&sP[t * 72 + p0];
  }
}

// ------ y16 = bf16(rmsnorm(y16 * silu(z)) * normw), in place ------
__global__ void rms_kernel(short* __restrict__ y, const float* __restrict__ Z,
                           const float* __restrict__ normw)
{
  const int row = blockIdx.x;
  const int lane = threadIdx.x;
  short* yr = y + (size_t)row * 1024;
  const float* zr = Z + (size_t)row * 2320;
  float vals[16];
  float ss = 0.f;
#pragma unroll
  for (int jj = 0; jj < 4; jj++) {
    int off = jj * 256 + lane * 4;
    short4 yv = *(short4*)(yr + off);
    float4 zv = *(const float4*)(zr + off);
    float a0 = bf2f(yv.x) * (zv.x * sigf(zv.x));
    float a1 = bf2f(yv.y) * (zv.y * sigf(zv.y));
    float a2 = bf2f(yv.z) * (zv.z * sigf(zv.z));
    float a3 = bf2f(yv.w) * (zv.w * sigf(zv.w));
    vals[jj * 4 + 0] = a0; vals[jj * 4 + 1] = a1;
    vals[jj * 4 + 2] = a2; vals[jj * 4 + 3] = a3;
    ss += a0 * a0 + a1 * a1 + a2 * a2 + a3 * a3;
  }
#pragma unroll
  for (int o = 32; o >= 1; o >>= 1) ss += __shfl_xor(ss, o);
  const float scale = rsqrtf(ss * (1.f / 1024.f) + 1e-5f);
#pragma unroll
  for (int jj = 0; jj < 4; jj++) {
    int off = jj * 256 + lane * 4;
    float4 nw = *(const float4*)(normw + off);
    *(short4*)(yr + off) = make_short4(
        f2bf(vals[jj * 4 + 0] * scale * nw.x), f2bf(vals[jj * 4 + 1] * scale * nw.y),
        f2bf(vals[jj * 4 + 2] * scale * nw.z), f2bf(vals[jj * 4 + 3] * scale * nw.w));
  }
}

// ---- ob16 = bf16(od * silu(h)) over 8192x512 ----
__global__ void combine_kernel(const float* __restrict__ od, const float* __restrict__ h,
                               short* __restrict__ ob)
{
  size_t idx = (size_t)blockIdx.x * 256 + threadIdx.x;
  float4 o = ((const float4*)od)[idx];
  float4 g = ((const float4*)h)[idx];
  o.x *= g.x * sigf(g.x);
  o.y *= g.y * sigf(g.y);
  o.z *= g.z * sigf(g.z);
  o.w *= g.w * sigf(g.w);
  *(short4*)(ob + idx * 4) = make_short4(f2bf(o.x), f2bf(o.y), f2bf(o.z), f2bf(o.w));
}

__global__ void lnshort_kernel(const float* __restrict__ v, const float* __restrict__ g,
                               const float* __restrict__ b, const float* __restrict__ shortcut,
                               float* __restrict__ out0, short* __restrict__ fn)
{
  const int row = blockIdx.x;
  const int lane = threadIdx.x;
  size_t base = (size_t)row * 256;
  float4 x = *(const float4*)(v + base + lane * 4);
  float sum = x.x + x.y + x.z + x.w;
#pragma unroll
  for (int o = 32; o >= 1; o >>= 1) sum += __shfl_xor(sum, o);
  const float mu = sum * (1.f / 256.f);
  float d[4] = {x.x - mu, x.y - mu, x.z - mu, x.w - mu};
  float vs = d[0] * d[0] + d[1] * d[1] + d[2] * d[2] + d[3] * d[3];
#pragma unroll
  for (int o = 32; o >= 1; o >>= 1) vs += __shfl_xor(vs, o);
  const float inv = rsqrtf(vs * (1.f / 256.f) + 1e-5f);
  float4 gg = *(const float4*)(g + lane * 4);
  float4 bb = *(const float4*)(b + lane * 4);
  float4 sc = *(const float4*)(shortcut + base + lane * 4);
  float4 o4;
  o4.x = d[0] * inv * gg.x + bb.x + sc.x;
  o4.y = d[1] * inv * gg.y + bb.y + sc.y;
  o4.z = d[2] * inv * gg.z + bb.z + sc.z;
  o4.w = d[3] * inv * gg.w + bb.w + sc.w;
  *(float4*)(out0 + base + lane * 4) = o4;
  float ns = o4.x * o4.x + o4.y * o4.y + o4.z * o4.z + o4.w * o4.w;
#pragma unroll
  for (int o = 32; o >= 1; o >>= 1) ns += __shfl_xor(ns, o);
  const float r = 1.f / fmaxf(sqrtf(ns), 1e-12f);
  *(short4*)(fn + base + lane * 4) =
      make_short4(f2bf(o4.x * r), f2bf(o4.y * r), f2bf(o4.z * r), f2bf(o4.w * r));
}

extern "C" void kernel_launch(void* const* d_in, const int* in_sizes, int n_in,
                              void* d_out, int out_size, void* d_ws, size_t ws_size,
                              hipStream_t stream)
{
  (void)in_sizes; (void)n_in; (void)out_size; (void)ws_size;
  const float* x        = (const float*)d_in[0];
  const float* Wp       = (const float*)d_in[1];
  const float* bp       = (const float*)d_in[2];
  const float* Wpre     = (const float*)d_in[3];
  const float* bpre     = (const float*)d_in[4];
  const float* lnpre_g  = (const float*)d_in[5];
  const float* lnpre_b  = (const float*)d_in[6];
  const float* Wpost    = (const float*)d_in[7];
  const float* bpost    = (const float*)d_in[8];
  const float* lnpost_g = (const float*)d_in[9];
  const float* lnpost_b = (const float*)d_in[10];

  float* ws   = (float*)d_ws;
  float* Zb   = ws;                        // 19,005,440
  float* xcv  = Zb + 19005440;             // 10,485,760 (+overlays below)
  float* xc   = xcv + 10485760;            // 2,097,152
  float* hbuf = xc + 2097152;              // 4,194,304
  short* hb16 = (short*)(hbuf + 4194304);  // 2,097,152 fl
  float* yb16f= hbuf + 4194304 + 2097152;  // 4,194,304 fl
  short* yb16 = (short*)yb16f;
  float* od   = yb16f + 4194304;           // 4,194,304
  float* dtv  = od + 4194304;              // 131,072
  float* ldA  = dtv + 131072;              // 131,072
  float* Pbuf = ldA + 131072;              // 2,048
  short* WinT = (short*)(Pbuf + 2048);     // 2432x512 sh
  short* WoutT= WinT + 1245184;            // 512x1024 sh

  short* Ag16   = (short*)xcv;                 // 8192x768 sh (until gather gemm)
  short* WpT    = (short*)(xcv + 3145728);     // 256x768 sh
  short* xcb    = (short*)xcv;                 // 8192x256 sh (until pre gemm)
  short* WpreT  = (short*)(xcv + 1048576);     // 512x256 sh
  short* ob16   = (short*)xcv;                 // 8192x512 sh (after xcv dead)
  short* WpostT = (short*)(xcv + 2097152);     // 256x512 sh (past ob16)
  float* vbuf = yb16f;
  short* fn16 = (short*)(yb16f + 2097152);

  float* out0 = (float*)d_out;
  float* attn = out0 + 2097152;
  float* Sbuf = attn;

  tcast_kernel<<<dim3(8, 24), 256, 0, stream>>>(Wp, WpT, 768, 256);
  gather_cast_kernel<<<6144, 256, 0, stream>>>(x, Ag16);
  gemm16_kernel<true, false><<<dim3(64, 2), 256, 0, stream>>>(Ag16, WpT, bp, xc, 8192, 256, 768, 256, 0, 0, 0);
  cast_kernel<<<2048, 256, 0, stream>>>(xc, xcb);
  tcast_kernel<<<dim3(16, 8), 256, 0, stream>>>(Wpre, WpreT, 256, 512);
  gemm16_kernel<true, false><<<dim3(64, 4), 256, 0, stream>>>(xcb, WpreT, bpre, hbuf, 8192, 512, 256, 512, 0, 0, 0);
  ln512_kernel<<<8192, 64, 0, stream>>>(hbuf, lnpre_g, lnpre_b, hb16);

  for (int dir = 0; dir < 2; dir++) {
    const float* Win   = (const float*)d_in[11 + dir * 8];
    const float* convw = (const float*)d_in[12 + dir * 8];
    const float* convb = (const float*)d_in[13 + dir * 8];
    const float* dtb   = (const float*)d_in[14 + dir * 8];
    const float* Alog  = (const float*)d_in[15 + dir * 8];
    const float* Dh    = (const float*)d_in[16 + dir * 8];
    const float* normw = (const float*)d_in[17 + dir * 8];
    const float* Wout  = (const float*)d_in[18 + dir * 8];

    tcast_kernel<<<dim3(76, 16), 256, 0, stream>>>(Win, WinT, 512, 2320);
    tcast_kernel<<<dim3(16, 32), 256, 0, stream>>>(Wout, WoutT, 1024, 512);
    gemm16_kernel<false, false><<<dim3(64, 19), 256, 0, stream>>>(hb16, WinT, nullptr, Zb, 8192, 2320, 512, 2320, 0, 0, 0);
    dtprep_kernel<<<512, 256, 0, stream>>>(Zb, dtb, Alog, dtv, ldA);
    conv_kernel<<<dim3(8192, 5), 256, 0, stream>>>(Zb, convw, convb, xcv, dir);
    chunk_state_kernel<<<dim3(64, 32), 256, 0, stream>>>(xcv, dtv, ldA, Sbuf, Pbuf, dir);
    chunk_scan_kernel<<<2048, 256, 0, stream>>>(Sbuf, Pbuf);
    chunk_out_kernel<<<dim3(64, 32), 256, 71168, stream>>>(xcv, dtv, ldA, Sbuf, Dh, yb16, dir);
    rms_kernel<<<8192, 64, 0, stream>>>(yb16, Zb, normw);
    if (dir == 0)
      gemm16_kernel<false, false><<<dim3(64, 4), 256, 0, stream>>>(yb16, WoutT, nullptr, od, 8192, 512, 1024, 512, 0, 0, 0);
    else
      gemm16_kernel<false, true><<<dim3(64, 4), 256, 0, stream>>>(yb16, WoutT, nullptr, od, 8192, 512, 1024, 512, 0, 0, 0);
  }

  combine_kernel<<<4096, 256, 0, stream>>>(od, hbuf, ob16);
  tcast_kernel<<<dim3(8, 16), 256, 0, stream>>>(Wpost, WpostT, 512, 256);
  gemm16_kernel<true, false><<<dim3(64, 2), 256, 0, stream>>>(ob16, WpostT, bpost, vbuf, 8192, 256, 512, 256, 0, 0, 0);
  lnshort_kernel<<<8192, 64, 0, stream>>>(vbuf, lnpost_g, lnpost_b, xc, out0, fn16);
  gemm16_kernel<false, false><<<dim3(16, 16, 4), 256, 0, stream>>>(
      fn16, fn16, nullptr, attn, 2048, 2048, 256, 2048,
      (long long)2048 * 256, (long long)2048 * 256, (long long)2048 * 2048);
}

// Round 6
// 651.551 us; speedup vs baseline: 5.5753x; 1.1215x over previous
//
#include <hip/hip_runtime.h>
#include <math.h>

__device__ __forceinline__ float sigf(float v) { return 1.f / (1.f + __expf(-v)); }

__device__ __forceinline__ short f2bf(float f) {
  unsigned int u = __builtin_bit_cast(unsigned int, f);
  unsigned int r = (u + 0x7fffu + ((u >> 16) & 1u)) >> 16;
  return (short)r;
}
__device__ __forceinline__ float bf2f(short s) {
  unsigned int u = ((unsigned int)(unsigned short)s) << 16;
  return __builtin_bit_cast(float, u);
}

typedef short bf16x8 __attribute__((ext_vector_type(8)));
typedef float f32x4 __attribute__((ext_vector_type(4)));

__device__ __forceinline__ void async16(const short* g, short* l) {
  __builtin_amdgcn_global_load_lds(
      (const __attribute__((address_space(1))) unsigned int*)g,
      (__attribute__((address_space(3))) unsigned int*)l, 16, 0, 0);
}

// ============ bf16 MFMA GEMM: C[M,N] += A[M,K] @ Bt[N,K]^T ============
template<bool BIAS, bool ACC>
__global__ __launch_bounds__(256) void gemm16_kernel(
    const short* __restrict__ A, const short* __restrict__ Bt,
    const float* __restrict__ bias, float* __restrict__ C,
    int M, int N, int K, int ldc,
    long long sAb, long long sBb, long long sCb)
{
  __shared__ short smA[128 * 32];
  __shared__ short smB[128 * 32];
  const int tid = threadIdx.x;
  const int wave = tid >> 6;
  const int lane = tid & 63;
  const int m0 = blockIdx.x * 128;
  const int n0 = blockIdx.y * 128;
  const int bz = blockIdx.z;
  const short* Ab = A + (size_t)bz * sAb;
  const short* Bb = Bt + (size_t)bz * sBb;
  float* Cb = C + (size_t)bz * sCb;

  f32x4 acc[4][4] = {};

  const int isB = wave >> 1;
  const int half = wave & 1;
  const short* gsrc = isB ? Bb : Ab;
  short* ldsbase = isB ? smB : smA;
  const int tile_r0 = isB ? n0 : m0;
  const int lrow = lane >> 2;
  const int lk = (lane & 3) * 8;

  const int wm = wave >> 1, wn = wave & 1;

  for (int k0 = 0; k0 < K; k0 += 32) {
#pragma unroll
    for (int c = 0; c < 4; c++) {
      int row = half * 64 + c * 16 + lrow;
      const short* g = gsrc + (size_t)(tile_r0 + row) * K + k0 + lk;
      short* l = ldsbase + (half * 64 + c * 16) * 32;
      async16(g, l);
    }
    __syncthreads();
    bf16x8 af[4], bfr[4];
#pragma unroll
    for (int mt = 0; mt < 4; mt++)
      af[mt] = *(bf16x8*)&smA[(wm * 64 + mt * 16 + (lane & 15)) * 32 + (lane >> 4) * 8];
#pragma unroll
    for (int nt = 0; nt < 4; nt++)
      bfr[nt] = *(bf16x8*)&smB[(wn * 64 + nt * 16 + (lane & 15)) * 32 + (lane >> 4) * 8];
#pragma unroll
    for (int mt = 0; mt < 4; mt++)
#pragma unroll
      for (int nt = 0; nt < 4; nt++)
        acc[mt][nt] = __builtin_amdgcn_mfma_f32_16x16x32_bf16(af[mt], bfr[nt], acc[mt][nt], 0, 0, 0);
    __syncthreads();
  }
#pragma unroll
  for (int nt = 0; nt < 4; nt++) {
    int col = n0 + wn * 64 + nt * 16 + (lane & 15);
    if (col >= N) continue;
    float bval = BIAS ? bias[col] : 0.f;
#pragma unroll
    for (int mt = 0; mt < 4; mt++) {
      int rowb = m0 + wm * 64 + mt * 16 + (lane >> 4) * 4;
#pragma unroll
      for (int r = 0; r < 4; r++) {
        float v = acc[mt][nt][r] + bval;
        float* cp = Cb + (size_t)(rowb + r) * ldc + col;
        if (ACC) v += *cp;
        *cp = v;
      }
    }
  }
}

// ---- transpose+cast: W[K][N] fp32 -> Wt[Np][K] bf16 (zero pad rows >= N) ----
__global__ void tcast_kernel(const float* __restrict__ W, short* __restrict__ Wt,
                             int K, int N)
{
  __shared__ float tile[32][33];
  int n0 = blockIdx.x * 32, k0 = blockIdx.y * 32;
  int c = threadIdx.x & 31, r8 = threadIdx.x >> 5;
#pragma unroll
  for (int i = 0; i < 4; i++) {
    int r = r8 + i * 8;
    int n = n0 + c;
    tile[r][c] = (n < N) ? W[(size_t)(k0 + r) * N + n] : 0.f;
  }
  __syncthreads();
#pragma unroll
  for (int i = 0; i < 4; i++) {
    int r = r8 + i * 8;
    Wt[(size_t)(n0 + r) * K + k0 + c] = f2bf(tile[c][r]);
  }
}

// ---- gather+cast: Ag16[m][s*256+d] = x[b][s][t][d], m=b*2048+t ----
__global__ void gather_cast_kernel(const float* __restrict__ x, short* __restrict__ Ag)
{
  int idx = blockIdx.x * 256 + threadIdx.x;
  int m = idx / 192;
  int g = idx - m * 192;
  int k = g * 4;
  int s = k >> 8, d = k & 255;
  int b = m >> 11, t = m & 2047;
  float4 v = *(const float4*)(x + ((size_t)((b * 3 + s) * 2048 + t) << 8) + d);
  *(short4*)(Ag + (size_t)m * 768 + k) = make_short4(f2bf(v.x), f2bf(v.y), f2bf(v.z), f2bf(v.w));
}

__global__ void cast_kernel(const float* __restrict__ in, short* __restrict__ out)
{
  size_t idx = (size_t)blockIdx.x * 256 + threadIdx.x;
  float4 v = *(const float4*)(in + idx * 4);
  *(short4*)(out + idx * 4) = make_short4(f2bf(v.x), f2bf(v.y), f2bf(v.z), f2bf(v.w));
}

// ---------------- LayerNorm over 512, in place + bf16 copy ----------------
__global__ void ln512_kernel(float* __restrict__ xio, const float* __restrict__ g,
                             const float* __restrict__ b, short* __restrict__ o16)
{
  const int row = blockIdx.x;
  const int lane = threadIdx.x;
  float* xr = xio + (size_t)row * 512;
  float4 v0 = *(float4*)(xr + lane * 4);
  float4 v1 = *(float4*)(xr + 256 + lane * 4);
  float sum = v0.x + v0.y + v0.z + v0.w + v1.x + v1.y + v1.z + v1.w;
#pragma unroll
  for (int o = 32; o >= 1; o >>= 1) sum += __shfl_xor(sum, o);
  const float mu = sum * (1.f / 512.f);
  float d[8] = {v0.x - mu, v0.y - mu, v0.z - mu, v0.w - mu,
                v1.x - mu, v1.y - mu, v1.z - mu, v1.w - mu};
  float vs = 0.f;
#pragma unroll
  for (int i = 0; i < 8; i++) vs += d[i] * d[i];
#pragma unroll
  for (int o = 32; o >= 1; o >>= 1) vs += __shfl_xor(vs, o);
  const float inv = rsqrtf(vs * (1.f / 512.f) + 1e-5f);
  float4 g0 = *(const float4*)(g + lane * 4);
  float4 g1 = *(const float4*)(g + 256 + lane * 4);
  float4 b0 = *(const float4*)(b + lane * 4);
  float4 b1 = *(const float4*)(b + 256 + lane * 4);
  v0.x = d[0] * inv * g0.x + b0.x; v0.y = d[1] * inv * g0.y + b0.y;
  v0.z = d[2] * inv * g0.z + b0.z; v0.w = d[3] * inv * g0.w + b0.w;
  v1.x = d[4] * inv * g1.x + b1.x; v1.y = d[5] * inv * g1.y + b1.y;
  v1.z = d[6] * inv * g1.z + b1.z; v1.w = d[7] * inv * g1.w + b1.w;
  *(float4*)(xr + lane * 4) = v0;
  *(float4*)(xr + 256 + lane * 4) = v1;
  short* orow = o16 + (size_t)row * 512;
  *(short4*)(orow + lane * 4) = make_short4(f2bf(v0.x), f2bf(v0.y), f2bf(v0.z), f2bf(v0.w));
  *(short4*)(orow + 256 + lane * 4) = make_short4(f2bf(v1.x), f2bf(v1.y), f2bf(v1.z), f2bf(v1.w));
}

// --------- dt = softplus(raw + dtb), logdA = -dt * exp(Alog) ---------
__global__ void dtprep_kernel(const float* __restrict__ Z, const float* __restrict__ dtb,
                              const float* __restrict__ Alog,
                              float* __restrict__ dtv, float* __restrict__ ldA)
{
  int idx = blockIdx.x * 256 + threadIdx.x;
  int row = idx >> 4, hh = idx & 15;
  float raw = Z[(size_t)row * 2320 + 2304 + hh] + dtb[hh];
  float dt = raw > 20.f ? raw : log1pf(expf(raw));
  dtv[idx] = dt;
  ldA[idx] = -dt * expf(Alog[hh]);
}

// ---- depthwise conv(4) + bias + silu, bf16 out ----
__global__ void conv_kernel(const float* __restrict__ Z, const float* __restrict__ convw,
                            const float* __restrict__ convb, short* __restrict__ xcv, int dir)
{
  int row = blockIdx.x;
  int c = blockIdx.y * 256 + threadIdx.x;
  int t = row & 2047;
  size_t bbase = (size_t)(row - t) * 2320;
  float wv[4] = {convw[c * 4 + 0], convw[c * 4 + 1], convw[c * 4 + 2], convw[c * 4 + 3]};
  float acc = convb[c];
#pragma unroll
  for (int k = 0; k < 4; k++) {
    int ts = dir ? (t + 3 - k) : (t - 3 + k);
    if (ts >= 0 && ts < 2048)
      acc += wv[k] * Z[bbase + (size_t)ts * 2320 + 1024 + c];
  }
  xcv[(size_t)row * 1280 + c] = f2bf(acc * sigf(acc));
}

// ============ chunked SSD scan, Lc=64, 32 chunks ============
// chunk_state (MFMA): S[p][n] = sum_s x_s[p] * (w_s B_s[n]); bf16 out
__global__ __launch_bounds__(256) void chunk_state_kernel(
    const short* __restrict__ xcv, const float* __restrict__ dtv,
    const float* __restrict__ ldA, short* __restrict__ Sbuf,
    float* __restrict__ Pbuf, int dir)
{
  __shared__ float sw[64];
  __shared__ short sXT[64 * 72];    // [p][s]
  __shared__ short sBw[128 * 72];   // [n][s], weight folded
  const int bh = blockIdx.x, ck = blockIdx.y;
  const int b = bh >> 4, h = bh & 15;
  const int tid = threadIdx.x;
  const int wave = tid >> 6, lane = tid & 63;

  if (tid < 64) {
    int tg = ck * 64 + tid;
    int tt = dir ? 2047 - tg : tg;
    size_t r = (size_t)(b * 2048 + tt) * 16 + h;
    float v = ldA[r];
#pragma unroll
    for (int o = 1; o < 64; o <<= 1) { float u = __shfl_up(v, o); if (tid >= o) v += u; }
    float tot = __shfl(v, 63);
    sw[tid] = __expf(tot - v) * dtv[r];
    if (tid == 63) Pbuf[bh * 32 + ck] = __expf(tot);
  }
  __syncthreads();
  // stage X^T [p][s]
  for (int i4 = tid; i4 < 512; i4 += 256) {
    int s = i4 >> 3, p0 = (i4 & 7) * 8;
    int tg = ck * 64 + s; int tt = dir ? 2047 - tg : tg;
    bf16x8 xv = *(const bf16x8*)(xcv + (size_t)(b * 2048 + tt) * 1280 + h * 64 + p0);
#pragma unroll
    for (int j = 0; j < 8; j++) sXT[(p0 + j) * 72 + s] = xv[j];
  }
  // stage (w*B)^T [n][s]
  for (int i4 = tid; i4 < 1024; i4 += 256) {
    int s = i4 >> 4, n0 = (i4 & 15) * 8;
    int tg = ck * 64 + s; int tt = dir ? 2047 - tg : tg;
    bf16x8 bv = *(const bf16x8*)(xcv + (size_t)(b * 2048 + tt) * 1280 + 1024 + n0);
    float w = sw[s];
#pragma unroll
    for (int j = 0; j < 8; j++) sBw[(n0 + j) * 72 + s] = f2bf(w * bf2f(bv[j]));
  }
  __syncthreads();

  const int mcol = lane & 15, kgrp = (lane >> 4) * 8;
  bf16x8 af[2];
#pragma unroll
  for (int kk = 0; kk < 2; kk++)
    af[kk] = *(bf16x8*)&sXT[(wave * 16 + mcol) * 72 + kk * 32 + kgrp];
  f32x4 acc[8] = {};
#pragma unroll
  for (int j = 0; j < 8; j++)
#pragma unroll
    for (int kk = 0; kk < 2; kk++) {
      bf16x8 bf = *(bf16x8*)&sBw[(j * 16 + mcol) * 72 + kk * 32 + kgrp];
      acc[j] = __builtin_amdgcn_mfma_f32_16x16x32_bf16(af[kk], bf, acc[j], 0, 0, 0);
    }
  short* Sp = Sbuf + ((size_t)(bh * 32 + ck) << 13);
  const int rbase = wave * 16 + (lane >> 4) * 4;
#pragma unroll
  for (int j = 0; j < 8; j++) {
    int n = j * 16 + mcol;
#pragma unroll
    for (int r = 0; r < 4; r++)
      Sp[(rbase + r) * 128 + n] = f2bf(acc[j][r]);
  }
}

// chunk_scan: in place on bf16 S, fp32 accumulate. 2 elems/thread.
__global__ void chunk_scan_kernel(short* __restrict__ Sbuf, const float* __restrict__ Pbuf)
{
  int idx = blockIdx.x * 256 + threadIdx.x;    // 64 bh x 4096 pairs
  int bh = idx >> 12, pr = idx & 4095;
  float h0 = 0.f, h1 = 0.f;
  for (int ck = 0; ck < 32; ck++) {
    size_t off = ((size_t)(bh * 32 + ck) << 13) + pr * 2;
    unsigned int u = *(const unsigned int*)(Sbuf + off);
    float s0 = bf2f((short)(u & 0xffff));
    float s1 = bf2f((short)(u >> 16));
    float P = Pbuf[bh * 32 + ck];
    unsigned int w = (unsigned int)(unsigned short)f2bf(h0) |
                     ((unsigned int)(unsigned short)f2bf(h1) << 16);
    *(unsigned int*)(Sbuf + off) = w;
    h0 = P * h0 + s0;
    h1 = P * h1 + s1;
  }
}

// ======== chunk_out (MFMA): y = P@X + exp(L_t)*(C@H^T) + Dh*x, bf16 out ========
__global__ __launch_bounds__(256) void chunk_out_kernel(
    const short* __restrict__ xcv, const float* __restrict__ dtv,
    const float* __restrict__ ldA, const short* __restrict__ Sbuf,
    const float* __restrict__ Dh, short* __restrict__ y, int dir)
{
  extern __shared__ short smem16[];
  short* sC  = smem16;            // [64][136]
  short* sB  = sC + 64 * 136;     // [64][136]
  short* sH  = sB + 64 * 136;     // [64][136]
  short* sXT = sH + 64 * 136;     // [64][72]
  short* sP  = sXT + 64 * 72;     // [64][72]; later y[t][p]
  float* sL  = (float*)(sP + 64 * 72);
  float* sdt = sL + 64;

  const int bh = blockIdx.x, ck = blockIdx.y;
  const int b = bh >> 4, h = bh & 15;
  const int tid = threadIdx.x;
  const int wave = tid >> 6, lane = tid & 63;

  if (tid < 64) {
    int tg = ck * 64 + tid;
    int tt = dir ? 2047 - tg : tg;
    size_t r = (size_t)(b * 2048 + tt) * 16 + h;
    float v = ldA[r];
#pragma unroll
    for (int o = 1; o < 64; o <<= 1) { float u = __shfl_up(v, o); if (tid >= o) v += u; }
    sL[tid] = v;
    sdt[tid] = dtv[r];
  }
  // stage C, B
  for (int i4 = tid; i4 < 1024; i4 += 256) {
    int t = i4 >> 4, c8 = (i4 & 15) * 8;
    int tg = ck * 64 + t; int tt = dir ? 2047 - tg : tg;
    const short* rp = xcv + (size_t)(b * 2048 + tt) * 1280;
    *(bf16x8*)&sB[t * 136 + c8] = *(const bf16x8*)(rp + 1024 + c8);
    *(bf16x8*)&sC[t * 136 + c8] = *(const bf16x8*)(rp + 1152 + c8);
  }
  // stage X^T
  for (int i4 = tid; i4 < 512; i4 += 256) {
    int t = i4 >> 3, p0 = (i4 & 7) * 8;
    int tg = ck * 64 + t; int tt = dir ? 2047 - tg : tg;
    bf16x8 xv = *(const bf16x8*)(xcv + (size_t)(b * 2048 + tt) * 1280 + h * 64 + p0);
#pragma unroll
    for (int j = 0; j < 8; j++) sXT[(p0 + j) * 72 + t] = xv[j];
  }
  // stage H (bf16)
  const short* Hp = Sbuf + ((size_t)(bh * 32 + ck) << 13);
  for (int i4 = tid; i4 < 1024; i4 += 256) {
    int p = i4 >> 4, c8 = (i4 & 15) * 8;
    *(bf16x8*)&sH[p * 136 + c8] = *(const bf16x8*)(Hp + p * 128 + c8);
  }
  __syncthreads();

  const int mcol = lane & 15;
  const int kgrp = (lane >> 4) * 8;
  const int mrow = wave * 16 + mcol;

  bf16x8 afC[4];
#pragma unroll
  for (int kk = 0; kk < 4; kk++)
    afC[kk] = *(bf16x8*)&sC[mrow * 136 + kk * 32 + kgrp];

  // scores
  f32x4 sacc[4] = {};
#pragma unroll
  for (int j = 0; j < 4; j++)
#pragma unroll
    for (int kk = 0; kk < 4; kk++) {
      bf16x8 bf = *(bf16x8*)&sB[(j * 16 + mcol) * 136 + kk * 32 + kgrp];
      sacc[j] = __builtin_amdgcn_mfma_f32_16x16x32_bf16(afC[kk], bf, sacc[j], 0, 0, 0);
    }

  const int rbase = wave * 16 + (lane >> 4) * 4;
  float Lt[4];
#pragma unroll
  for (int r = 0; r < 4; r++) Lt[r] = sL[rbase + r];
#pragma unroll
  for (int j = 0; j < 4; j++) {
    int s = j * 16 + mcol;
    float Ls = sL[s], ds = sdt[s];
#pragma unroll
    for (int r = 0; r < 4; r++) {
      int t = rbase + r;
      float v = (t >= s) ? sacc[j][r] * __expf(Lt[r] - Ls) * ds : 0.f;
      sP[t * 72 + s] = f2bf(v);
    }
  }
  __syncthreads();

  // intra: y1 = P @ X (K=64)
  bf16x8 afP[2];
#pragma unroll
  for (int kk = 0; kk < 2; kk++)
    afP[kk] = *(bf16x8*)&sP[mrow * 72 + kk * 32 + kgrp];
  f32x4 yacc[4] = {};
#pragma unroll
  for (int j = 0; j < 4; j++)
#pragma unroll
    for (int kk = 0; kk < 2; kk++) {
      bf16x8 bf = *(bf16x8*)&sXT[(j * 16 + mcol) * 72 + kk * 32 + kgrp];
      yacc[j] = __builtin_amdgcn_mfma_f32_16x16x32_bf16(afP[kk], bf, yacc[j], 0, 0, 0);
    }
  // inter: y2 = C @ H^T (K=128)
  f32x4 y2[4] = {};
#pragma unroll
  for (int j = 0; j < 4; j++)
#pragma unroll
    for (int kk = 0; kk < 4; kk++) {
      bf16x8 bf = *(bf16x8*)&sH[(j * 16 + mcol) * 136 + kk * 32 + kgrp];
      y2[j] = __builtin_amdgcn_mfma_f32_16x16x32_bf16(afC[kk], bf, y2[j], 0, 0, 0);
    }

  const float dh = Dh[h];
  float eL[4];
#pragma unroll
  for (int r = 0; r < 4; r++) eL[r] = __expf(Lt[r]);
#pragma unroll
  for (int j = 0; j < 4; j++) {
    int p = j * 16 + mcol;
#pragma unroll
    for (int r = 0; r < 4; r++) {
      float xv = bf2f(sXT[p * 72 + rbase + r]);
      yacc[j][r] = yacc[j][r] + eL[r] * y2[j][r] + dh * xv;
    }
  }
  __syncthreads();
#pragma unroll
  for (int j = 0; j < 4; j++) {
    int p = j * 16 + mcol;
#pragma unroll
    for (int r = 0; r < 4; r++)
      sP[(rbase + r) * 72 + p] = f2bf(yacc[j][r]);
  }
  __syncthreads();
  for (int i4 = tid; i4 < 1024; i4 += 256) {
    int t = i4 >> 4, p0 = (i4 & 15) * 4;
    int tg = ck * 64 + t; int tt = dir ? 2047 - tg : tg;
    *(short4*)(y + (size_t)(b * 2048 + tt) * 1024 + h * 64 + p0) = *(short4*)&sP[t * 72 + p0];
  }
}

// ------ y16 = bf16(rmsnorm(y16 * silu(z)) * normw), in place ------
__global__ void rms_kernel(short* __restrict__ y, const float* __restrict__ Z,
                           const float* __restrict__ normw)
{
  const int row = blockIdx.x;
  const int lane = threadIdx.x;
  short* yr = y + (size_t)row * 1024;
  const float* zr = Z + (size_t)row * 2320;
  float vals[16];
  float ss = 0.f;
#pragma unroll
  for (int jj = 0; jj < 4; jj++) {
    int off = jj * 256 + lane * 4;
    short4 yv = *(short4*)(yr + off);
    float4 zv = *(const float4*)(zr + off);
    float a0 = bf2f(yv.x) * (zv.x * sigf(zv.x));
    float a1 = bf2f(yv.y) * (zv.y * sigf(zv.y));
    float a2 = bf2f(yv.z) * (zv.z * sigf(zv.z));
    float a3 = bf2f(yv.w) * (zv.w * sigf(zv.w));
    vals[jj * 4 + 0] = a0; vals[jj * 4 + 1] = a1;
    vals[jj * 4 + 2] = a2; vals[jj * 4 + 3] = a3;
    ss += a0 * a0 + a1 * a1 + a2 * a2 + a3 * a3;
  }
#pragma unroll
  for (int o = 32; o >= 1; o >>= 1) ss += __shfl_xor(ss, o);
  const float scale = rsqrtf(ss * (1.f / 1024.f) + 1e-5f);
#pragma unroll
  for (int jj = 0; jj < 4; jj++) {
    int off = jj * 256 + lane * 4;
    float4 nw = *(const float4*)(normw + off);
    *(short4*)(yr + off) = make_short4(
        f2bf(vals[jj * 4 + 0] * scale * nw.x), f2bf(vals[jj * 4 + 1] * scale * nw.y),
        f2bf(vals[jj * 4 + 2] * scale * nw.z), f2bf(vals[jj * 4 + 3] * scale * nw.w));
  }
}

// ---- ob16 = bf16(od * silu(h)) over 8192x512 ----
__global__ void combine_kernel(const float* __restrict__ od, const float* __restrict__ h,
                               short* __restrict__ ob)
{
  size_t idx = (size_t)blockIdx.x * 256 + threadIdx.x;
  float4 o = ((const float4*)od)[idx];
  float4 g = ((const float4*)h)[idx];
  o.x *= g.x * sigf(g.x);
  o.y *= g.y * sigf(g.y);
  o.z *= g.z * sigf(g.z);
  o.w *= g.w * sigf(g.w);
  *(short4*)(ob + idx * 4) = make_short4(f2bf(o.x), f2bf(o.y), f2bf(o.z), f2bf(o.w));
}

__global__ void lnshort_kernel(const float* __restrict__ v, const float* __restrict__ g,
                               const float* __restrict__ b, const float* __restrict__ shortcut,
                               float* __restrict__ out0, short* __restrict__ fn)
{
  const int row = blockIdx.x;
  const int lane = threadIdx.x;
  size_t base = (size_t)row * 256;
  float4 x = *(const float4*)(v + base + lane * 4);
  float sum = x.x + x.y + x.z + x.w;
#pragma unroll
  for (int o = 32; o >= 1; o >>= 1) sum += __shfl_xor(sum, o);
  const float mu = sum * (1.f / 256.f);
  float d[4] = {x.x - mu, x.y - mu, x.z - mu, x.w - mu};
  float vs = d[0] * d[0] + d[1] * d[1] + d[2] * d[2] + d[3] * d[3];
#pragma unroll
  for (int o = 32; o >= 1; o >>= 1) vs += __shfl_xor(vs, o);
  const float inv = rsqrtf(vs * (1.f / 256.f) + 1e-5f);
  float4 gg = *(const float4*)(g + lane * 4);
  float4 bb = *(const float4*)(b + lane * 4);
  float4 sc = *(const float4*)(shortcut + base + lane * 4);
  float4 o4;
  o4.x = d[0] * inv * gg.x + bb.x + sc.x;
  o4.y = d[1] * inv * gg.y + bb.y + sc.y;
  o4.z = d[2] * inv * gg.z + bb.z + sc.z;
  o4.w = d[3] * inv * gg.w + bb.w + sc.w;
  *(float4*)(out0 + base + lane * 4) = o4;
  float ns = o4.x * o4.x + o4.y * o4.y + o4.z * o4.z + o4.w * o4.w;
#pragma unroll
  for (int o = 32; o >= 1; o >>= 1) ns += __shfl_xor(ns, o);
  const float r = 1.f / fmaxf(sqrtf(ns), 1e-12f);
  *(short4*)(fn + base + lane * 4) =
      make_short4(f2bf(o4.x * r), f2bf(o4.y * r), f2bf(o4.z * r), f2bf(o4.w * r));
}

extern "C" void kernel_launch(void* const* d_in, const int* in_sizes, int n_in,
                              void* d_out, int out_size, void* d_ws, size_t ws_size,
                              hipStream_t stream)
{
  (void)in_sizes; (void)n_in; (void)out_size; (void)ws_size;
  const float* x        = (const float*)d_in[0];
  const float* Wp       = (const float*)d_in[1];
  const float* bp       = (const float*)d_in[2];
  const float* Wpre     = (const float*)d_in[3];
  const float* bpre     = (const float*)d_in[4];
  const float* lnpre_g  = (const float*)d_in[5];
  const float* lnpre_b  = (const float*)d_in[6];
  const float* Wpost    = (const float*)d_in[7];
  const float* bpost    = (const float*)d_in[8];
  const float* lnpost_g = (const float*)d_in[9];
  const float* lnpost_b = (const float*)d_in[10];

  float* ws   = (float*)d_ws;
  float* Zb   = ws;                        // 19,005,440 fl
  float* xcvr = Zb + 19005440;             // 10,485,760 fl region (overlays)
  float* xc   = xcvr + 10485760;           // 2,097,152
  float* hbuf = xc + 2097152;              // 4,194,304
  short* hb16 = (short*)(hbuf + 4194304);  // 2,097,152 fl
  float* yb16f= hbuf + 4194304 + 2097152;  // 4,194,304 fl
  short* yb16 = (short*)yb16f;
  float* od   = yb16f + 4194304;           // 4,194,304
  float* dtv  = od + 4194304;              // 131,072
  float* ldA  = dtv + 131072;              // 131,072
  float* Pbuf = ldA + 131072;              // 2,048
  short* WinT = (short*)(Pbuf + 2048);     // 2432x512 sh
  short* WoutT= WinT + 1245184;            // 512x1024 sh

  short* xcv16  = (short*)xcvr;                // 8192x1280 sh = 5,242,880 fl (scan loop)
  short* Ag16   = (short*)xcvr;                // 8192x768 sh (until gather gemm)
  short* WpT    = (short*)(xcvr + 3145728);    // 256x768 sh
  short* xcb    = (short*)xcvr;                // 8192x256 sh (until pre gemm)
  short* WpreT  = (short*)(xcvr + 1048576);    // 512x256 sh
  short* ob16   = (short*)xcvr;                // 8192x512 sh (after xcv dead)
  short* WpostT = (short*)(xcvr + 2097152);    // 256x512 sh (past ob16)
  float* vbuf = yb16f;
  short* fn16 = (short*)(yb16f + 2097152);

  float* out0 = (float*)d_out;
  float* attn = out0 + 2097152;
  short* Sbuf16 = (short*)attn;                // 64*32*8192 sh (first half of attn region)

  tcast_kernel<<<dim3(8, 24), 256, 0, stream>>>(Wp, WpT, 768, 256);
  gather_cast_kernel<<<6144, 256, 0, stream>>>(x, Ag16);
  gemm16_kernel<true, false><<<dim3(64, 2), 256, 0, stream>>>(Ag16, WpT, bp, xc, 8192, 256, 768, 256, 0, 0, 0);
  cast_kernel<<<2048, 256, 0, stream>>>(xc, xcb);
  tcast_kernel<<<dim3(16, 8), 256, 0, stream>>>(Wpre, WpreT, 256, 512);
  gemm16_kernel<true, false><<<dim3(64, 4), 256, 0, stream>>>(xcb, WpreT, bpre, hbuf, 8192, 512, 256, 512, 0, 0, 0);
  ln512_kernel<<<8192, 64, 0, stream>>>(hbuf, lnpre_g, lnpre_b, hb16);

  for (int dir = 0; dir < 2; dir++) {
    const float* Win   = (const float*)d_in[11 + dir * 8];
    const float* convw = (const float*)d_in[12 + dir * 8];
    const float* convb = (const float*)d_in[13 + dir * 8];
    const float* dtb   = (const float*)d_in[14 + dir * 8];
    const float* Alog  = (const float*)d_in[15 + dir * 8];
    const float* Dh    = (const float*)d_in[16 + dir * 8];
    const float* normw = (const float*)d_in[17 + dir * 8];
    const float* Wout  = (const float*)d_in[18 + dir * 8];

    tcast_kernel<<<dim3(76, 16), 256, 0, stream>>>(Win, WinT, 512, 2320);
    tcast_kernel<<<dim3(16, 32), 256, 0, stream>>>(Wout, WoutT, 1024, 512);
    gemm16_kernel<false, false><<<dim3(64, 19), 256, 0, stream>>>(hb16, WinT, nullptr, Zb, 8192, 2320, 512, 2320, 0, 0, 0);
    dtprep_kernel<<<512, 256, 0, stream>>>(Zb, dtb, Alog, dtv, ldA);
    conv_kernel<<<dim3(8192, 5), 256, 0, stream>>>(Zb, convw, convb, xcv16, dir);
    chunk_state_kernel<<<dim3(64, 32), 256, 0, stream>>>(xcv16, dtv, ldA, Sbuf16, Pbuf, dir);
    chunk_scan_kernel<<<1024, 256, 0, stream>>>(Sbuf16, Pbuf);
    chunk_out_kernel<<<dim3(64, 32), 256, 71168, stream>>>(xcv16, dtv, ldA, Sbuf16, Dh, yb16, dir);
    rms_kernel<<<8192, 64, 0, stream>>>(yb16, Zb, normw);
    if (dir == 0)
      gemm16_kernel<false, false><<<dim3(64, 4), 256, 0, stream>>>(yb16, WoutT, nullptr, od, 8192, 512, 1024, 512, 0, 0, 0);
    else
      gemm16_kernel<false, true><<<dim3(64, 4), 256, 0, stream>>>(yb16, WoutT, nullptr, od, 8192, 512, 1024, 512, 0, 0, 0);
  }

  combine_kernel<<<4096, 256, 0, stream>>>(od, hbuf, ob16);
  tcast_kernel<<<dim3(8, 16), 256, 0, stream>>>(Wpost, WpostT, 512, 256);
  gemm16_kernel<true, false><<<dim3(64, 2), 256, 0, stream>>>(ob16, WpostT, bpost, vbuf, 8192, 256, 512, 256, 0, 0, 0);
  lnshort_kernel<<<8192, 64, 0, stream>>>(vbuf, lnpost_g, lnpost_b, xc, out0, fn16);
  gemm16_kernel<false, false><<<dim3(16, 16, 4), 256, 0, stream>>>(
      fn16, fn16, nullptr, attn, 2048, 2048, 256, 2048,
      (long long)2048 * 256, (long long)2048 * 256, (long long)2048 * 2048);
}